// Round 13
// baseline (293.095 us; speedup 1.0000x reference)
//
#include <hip/hip_runtime.h>
#include <math.h>

#define BQ 8
#define CC 2048
#define DDIM 128
#define LLAY 3
#define HH 4
#define KK 200
#define SSLOT 64
#define OUTN 24
#define DH 32

typedef __bf16 bf16_t;
typedef __bf16 bf16x8 __attribute__((ext_vector_type(8)));
typedef float f32x4 __attribute__((ext_vector_type(4)));

__device__ __forceinline__ float fastrcp(float x) {
#if __has_builtin(__builtin_amdgcn_rcpf)
  return __builtin_amdgcn_rcpf(x);
#else
  return 1.0f / x;
#endif
}
__device__ __forceinline__ float fastexp2(float x) {
#if __has_builtin(__builtin_amdgcn_exp2f)
  return __builtin_amdgcn_exp2f(x);
#else
  return exp2f(x);
#endif
}
// gelu tanh-approx: x - x/(1+e^y); inf/underflow give exact limits
__device__ __forceinline__ float fgelu2(float x) {
  float s = x * x;
  float inner = fmaf(0.044715f * s, x, x);
  float e = fastexp2(inner * 2.302118610509359f);  // 2*0.79788456*log2(e)
  float r = fastrcp(1.f + e);
  return fmaf(-x, r, x);
}
__device__ __forceinline__ float egelu(float x) {
  return 0.5f * x * (1.f + erff(x * 0.7071067811865476f));
}

// ---------------- prep: wconv (blocks 0..143) + topk+bind (144..151) -------
__global__ __launch_bounds__(256) void prep_kernel(
    const float* __restrict__ qW, const float* __restrict__ kW,
    const float* __restrict__ vW, const float* __restrict__ oW,
    const float* __restrict__ fW1, const float* __restrict__ fW2,
    bf16_t* __restrict__ wtb,
    const float* __restrict__ x, const float* __restrict__ role_emb,
    const float* __restrict__ fw, float* __restrict__ btok,
    bf16_t* __restrict__ btokbf) {
  __shared__ float Ts[64][65];
  __shared__ float svals[KK];
  __shared__ int sidx[KK];
  __shared__ int redbuf[2][4];
  __shared__ int cnt;
  const int blk = blockIdx.x, tid = threadIdx.x;
  if (blk < 144) {
    const int t = blk;
    const float* src; bf16_t* dst; int N, K, k0, n0;
    if (t < 48) {
      int which = t / 12, rem = t % 12;
      int l = rem >> 2, tt = rem & 3;
      N = 128; K = 128; k0 = (tt >> 1) * 64; n0 = (tt & 1) * 64;
      src = (which == 0 ? qW : which == 1 ? kW : which == 2 ? vW : oW) + l * 16384;
      dst = wtb + which * 49152 + l * 16384;
    } else if (t < 96) {
      int t2 = t - 48, l = t2 >> 4, tt = t2 & 15;
      N = 512; K = 128; k0 = (tt >> 3) * 64; n0 = (tt & 7) * 64;
      src = fW1 + l * 65536;
      dst = wtb + 196608 + l * 65536;
    } else {
      int t3 = t - 96, l = t3 >> 4, tt = t3 & 15;
      N = 128; K = 512; k0 = (tt >> 1) * 64; n0 = (tt & 1) * 64;
      src = fW2 + l * 65536;
      dst = wtb + 393216 + l * 65536;
    }
#pragma unroll
    for (int i = 0; i < 16; ++i) {
      int u = tid + i * 256;
      int r = u >> 6, c = u & 63;
      Ts[r][c] = src[(size_t)(k0 + r) * N + n0 + c];
    }
    __syncthreads();
#pragma unroll
    for (int i = 0; i < 16; ++i) {
      int u = tid + i * 256;
      int rn = u >> 6, ck = u & 63;
      dst[(size_t)(n0 + rn) * K + k0 + ck] = (bf16_t)Ts[ck][rn];
    }
    return;
  }
  // ---- top-k + bind for batch b ----
  const int b = blk - 144;
  const int w = tid >> 6, lane = tid & 63;
  float xv[8]; unsigned xb[8];
#pragma unroll
  for (int t = 0; t < 8; t++) {
    float v = x[b * CC + t * 256 + tid];
    xv[t] = v;
    xb[t] = __float_as_uint(v);
  }
  unsigned lo = 0u, hi = 0x7f800000u;
  int itn = 0;
  while (lo < hi) {                          // 1 barrier/iter (dbuf + ballot)
    unsigned mid = (lo + hi) >> 1;
    int c = 0;
#pragma unroll
    for (int t = 0; t < 8; t++) c += __popcll(__ballot(xb[t] > mid));
    if (lane == 0) redbuf[itn & 1][w] = c;
    __syncthreads();
    int ct = redbuf[itn & 1][0] + redbuf[itn & 1][1] +
             redbuf[itn & 1][2] + redbuf[itn & 1][3];
    if (ct >= KK) lo = mid + 1; else hi = mid;
    ++itn;
  }
  const unsigned thr = lo;
  if (tid == 0) cnt = 0;
  __syncthreads();
#pragma unroll
  for (int t = 0; t < 8; t++) {
    if (xb[t] > thr) {
      int p = atomicAdd(&cnt, 1);
      svals[p] = log1pf(xv[t]);
      sidx[p] = t * 256 + tid;
    }
  }
  __syncthreads();
#pragma unroll
  for (int t = 0; t < 8; t++) {
    if (xb[t] == thr) {
      int p = atomicAdd(&cnt, 1);
      if (p < KK) {
        svals[p] = log1pf(xv[t]);
        sidx[p] = t * 256 + tid;
      }
    }
  }
  __syncthreads();
  for (int u = tid; u < KK * DDIM; u += 256) {
    int dd = u & 127, t = u >> 7;
    float v = svals[t];
    float fill = egelu(v * fw[dd]);
    float val = role_emb[(size_t)sidx[t] * DDIM + dd] * fill;
    btok[(size_t)b * KK * DDIM + u] = val;
    btokbf[(size_t)b * KK * DDIM + u] = (bf16_t)val;
  }
}

// ---------------- qkv (layer 0 only): BM=32, grid (50,3); outputs bf16 -----
__global__ __launch_bounds__(256) void qkv_mfma(const bf16_t* __restrict__ A,
    const bf16_t* __restrict__ qWt, const float* __restrict__ qb,
    const bf16_t* __restrict__ kWt, const float* __restrict__ kb,
    const bf16_t* __restrict__ vWt, const float* __restrict__ vb,
    bf16_t* __restrict__ qo, bf16_t* __restrict__ ko, bf16_t* __restrict__ vo) {
  __shared__ __align__(16) bf16_t Alds[32 * 16 * 8];
  __shared__ __align__(16) bf16_t Blds[128 * 16 * 8];
  const int tid = threadIdx.x, m0 = blockIdx.x * 32, z = blockIdx.y;
  const bf16_t* Wt; const float* bias; bf16_t* C;
  if (z == 0) { Wt = qWt; bias = qb; C = qo; }
  else if (z == 1) { Wt = kWt; bias = kb; C = ko; }
  else { Wt = vWt; bias = vb; C = vo; }
#pragma unroll
  for (int it = 0; it < 2; ++it) {
    int u = tid + it * 256;                 // < 512
    int row = u >> 4, kc = u & 15;
    uint4 d = *(const uint4*)(A + (size_t)(m0 + row) * 128 + kc * 8);
    *(uint4*)&Alds[(row * 16 + (kc ^ (row & 7))) * 8] = d;
  }
#pragma unroll
  for (int it = 0; it < 8; ++it) {
    int u = tid + it * 256;
    int col = u >> 4, kcb = u & 15;
    uint4 d = *(const uint4*)(Wt + (size_t)col * 128 + kcb * 8);
    *(uint4*)&Blds[(col * 16 + (kcb ^ (col & 7))) * 8] = d;
  }
  __syncthreads();
  const int w = tid >> 6, lane = tid & 63, fcol = lane & 15, g = lane >> 4;
  const int wr = w & 1, wn = w >> 1;
  f32x4 acc[4];
#pragma unroll
  for (int ni = 0; ni < 4; ++ni) acc[ni] = (f32x4){0.f, 0.f, 0.f, 0.f};
#pragma unroll
  for (int ks = 0; ks < 4; ++ks) {
    const int arow = 16 * wr + fcol;
    bf16x8 a = *(const bf16x8*)&Alds[(arow * 16 + ((ks * 4 + g) ^ (arow & 7))) * 8];
#pragma unroll
    for (int ni = 0; ni < 4; ++ni) {
      const int bcol = wn * 64 + ni * 16 + fcol;
      bf16x8 b = *(const bf16x8*)&Blds[(bcol * 16 + ((ks * 4 + g) ^ (bcol & 7))) * 8];
      acc[ni] = __builtin_amdgcn_mfma_f32_16x16x32_bf16(a, b, acc[ni], 0, 0, 0);
    }
  }
#pragma unroll
  for (int ni = 0; ni < 4; ++ni) {
    const int col = wn * 64 + ni * 16 + fcol;
    const float bv = bias[col];
#pragma unroll
    for (int r = 0; r < 4; ++r) {
      const int row = m0 + 16 * wr + 4 * g + r;
      C[(size_t)row * 128 + col] = (bf16_t)(acc[ni][r] + bv);
    }
  }
}

// ---------------- fused relational attention v11: (512,8) -> 4 blocks/CU ---
__global__ __launch_bounds__(512, 8) void rel_attn_mfma(
    const bf16_t* __restrict__ qbf, const bf16_t* __restrict__ kbf,
    const bf16_t* __restrict__ vbf,
    const float* __restrict__ W1g, const float* __restrict__ b1g,
    const float* __restrict__ w2p, bf16_t* __restrict__ o) {
  __shared__ __align__(16) bf16_t ksh[208 * 32];   // 13312 B, 16B-block swizz
  __shared__ __align__(16) bf16_t vtsh[32 * 224];  // 14336 B, V^T [f'][j]
  __shared__ __align__(16) bf16_t psh[8 * 224];    // 3584 B, P [i][j]
  __shared__ __align__(16) bf16_t W1ki[32 * 66];   // 4224 B (k,i) pairs, +2 pad
  __shared__ __align__(16) bf16_t qsh[8 * 32];     // 512 B
  __shared__ __align__(16) bf16_t qtshb[8 * 32];   // 512 B    (sum 36480)
  const int tid = threadIdx.x;
  const int bh = blockIdx.y, bb = bh >> 2, h = bh & 3;
  const int i0 = blockIdx.x * 8;
  const bf16_t* kgb = kbf + (size_t)(bb * KK) * DDIM + h * DH;
  const bf16_t* vgb = vbf + (size_t)(bb * KK) * DDIM + h * DH;
  const bf16_t* qgb = qbf + (size_t)(bb * KK) * DDIM + h * DH;
  // ---- stage K (16B units, swizzled) ----
#pragma unroll
  for (int it = 0; it < 2; ++it) {
    int u = tid + it * 512;                 // < 832
    if (u < 832) {
      int j = u >> 2, bi = u & 3;
      uint4 d = {0u, 0u, 0u, 0u};
      if (j < KK) d = *(const uint4*)(kgb + (size_t)j * DDIM + bi * 8);
      *(uint4*)&ksh[j * 32 + (bi ^ ((j >> 1) & 3)) * 8] = d;
    }
  }
  // ---- stage V^T (stride 224, cols >=200 zero) ----
#pragma unroll
  for (int it = 0; it < 7; ++it) {
    int u = tid + it * 512;                 // < 3328 = 104 j-pairs * 32 f
    if (u < 3328) {
      int jp = u >> 5, f = u & 31;
      int j0 = jp * 2;
      bf16_t a0 = (j0 < KK) ? vgb[(size_t)j0 * DDIM + f] : (bf16_t)0.f;
      bf16_t a1 = (j0 + 1 < KK) ? vgb[(size_t)(j0 + 1) * DDIM + f] : (bf16_t)0.f;
      union { bf16_t h2[2]; unsigned uu; } pk;
      pk.h2[0] = a0; pk.h2[1] = a1;
      *(unsigned*)&vtsh[f * 224 + j0] = pk.uu;
    }
  }
  if (tid < 256) {                          // vtsh pad cols 208..223
    int f = tid >> 3, cp = tid & 7;
    *(unsigned*)&vtsh[f * 224 + 208 + cp * 2] = 0u;
  }
  if (tid < 64) {                           // psh pad cols 208..223
    int r = tid >> 3, cp = tid & 7;
    *(unsigned*)&psh[r * 224 + 208 + cp * 2] = 0u;
  }
  // ---- stage W1ki (bf16, stride 66) ----
#pragma unroll
  for (int it = 0; it < 4; ++it) {
    int u = tid + it * 512;                 // < 2048
    int sel = u & 1, f = (u >> 1) & 31, e = u >> 6;
    W1ki[e * 66 + f * 2 + sel] = (bf16_t)W1g[(32 + sel * 32 + e) * 32 + f];
  }
  // ---- stage q (bf16) ----
  if (tid < 128) {
    int il = tid >> 4, ep = tid & 15;
    *(unsigned*)&qsh[il * 32 + ep * 2] =
        *(const unsigned*)(qgb + (size_t)(i0 + il) * DDIM + ep * 2);
  }
  __syncthreads();
  // ---- qtv = q @ W1q + b1 (W1q from global; L2-hot) ----
  if (tid < 256) {
    int il = tid >> 5, f = tid & 31;
    float a = b1g[f];
#pragma unroll
    for (int e = 0; e < 32; ++e)
      a = fmaf((float)qsh[il * 32 + e], W1g[e * 32 + f], a);
    qtshb[il * 32 + f] = (bf16_t)a;
  }
  __syncthreads();
  const int w = tid >> 6, lane = tid & 63;
  const int fcol = lane & 15, g = lane >> 4;
  const float w2c = 0.17677669529663687f * 1.4426950408889634f;
  float4 w2a = *(const float4*)(w2p + 4 * g);
  float4 w2b = *(const float4*)(w2p + 16 + 4 * g);
  w2a.x *= w2c; w2a.y *= w2c; w2a.z *= w2c; w2a.w *= w2c;
  w2b.x *= w2c; w2b.y *= w2c; w2b.z *= w2c; w2b.w *= w2c;
  // ---- score phase: one query per wave (il = w) ----
  {
    const int il = w;
    bf16x8 qv8 = *(const bf16x8*)&qsh[il * 32 + g * 8];
    bf16x8 bw0, bw1;
#pragma unroll
    for (int e8 = 0; e8 < 8; ++e8) {
      int e = g * 8 + e8;
      float qe = (float)qv8[e8];
      union { unsigned u; bf16_t h[2]; } k0_, k1_;
      k0_.u = *(const unsigned*)&W1ki[e * 66 + fcol * 2];
      k1_.u = *(const unsigned*)&W1ki[e * 66 + (fcol + 16) * 2];
      bw0[e8] = (bf16_t)fmaf(qe, (float)k0_.h[1], (float)k0_.h[0]);
      bw1[e8] = (bf16_t)fmaf(qe, (float)k1_.h[1], (float)k1_.h[0]);
    }
    const bf16_t* qtp = &qtshb[il * 32];
    const f32x4 cin0 = {(float)qtp[4 * g + 0], (float)qtp[4 * g + 1],
                        (float)qtp[4 * g + 2], (float)qtp[4 * g + 3]};
    const f32x4 cin1 = {(float)qtp[16 + 4 * g + 0], (float)qtp[16 + 4 * g + 1],
                        (float)qtp[16 + 4 * g + 2], (float)qtp[16 + 4 * g + 3]};
    float s[13];
#pragma unroll
    for (int jt = 0; jt < 13; ++jt) {
      int j = jt * 16 + fcol;
      bf16x8 af = *(const bf16x8*)&ksh[j * 32 + (g ^ ((j >> 1) & 3)) * 8];
      f32x4 acc0 = __builtin_amdgcn_mfma_f32_16x16x32_bf16(bw0, af, cin0, 0, 0, 0);
      f32x4 acc1 = __builtin_amdgcn_mfma_f32_16x16x32_bf16(bw1, af, cin1, 0, 0, 0);
      float t0 = fgelu2(acc0[0]) * w2a.x;
      t0 = fmaf(fgelu2(acc0[1]), w2a.y, t0);
      float t1 = fgelu2(acc0[2]) * w2a.z;
      t1 = fmaf(fgelu2(acc0[3]), w2a.w, t1);
      float t2 = fgelu2(acc1[0]) * w2b.x;
      t2 = fmaf(fgelu2(acc1[1]), w2b.y, t2);
      float t3 = fgelu2(acc1[2]) * w2b.z;
      t3 = fmaf(fgelu2(acc1[3]), w2b.w, t3);
      float t = (t0 + t1) + (t2 + t3);
      t += __shfl_xor(t, 16);
      t += __shfl_xor(t, 32);
      s[jt] = t;
    }
    if (fcol >= 8) s[12] = -1e30f;          // mask j >= 200
    float m = s[0];
#pragma unroll
    for (int jt = 1; jt < 13; ++jt) m = fmaxf(m, s[jt]);
    m = fmaxf(m, __shfl_xor(m, 1));
    m = fmaxf(m, __shfl_xor(m, 2));
    m = fmaxf(m, __shfl_xor(m, 4));
    m = fmaxf(m, __shfl_xor(m, 8));
    float l = 0.f;
#pragma unroll
    for (int jt = 0; jt < 13; ++jt) {
      float p = fastexp2(s[jt] - m);
      s[jt] = p;
      l += p;
    }
    l += __shfl_xor(l, 1);
    l += __shfl_xor(l, 2);
    l += __shfl_xor(l, 4);
    l += __shfl_xor(l, 8);
    const float inv = fastrcp(l);
    if (g == 0) {
#pragma unroll
      for (int jt = 0; jt < 13; ++jt)
        psh[il * 224 + jt * 16 + fcol] = (bf16_t)(s[jt] * inv);
    }
  }
  __syncthreads();
  // ---- PV (waves 0,1) ----
  if (w < 2) {
    f32x4 acc = {0.f, 0.f, 0.f, 0.f};
#pragma unroll
    for (int ks = 0; ks < 7; ++ks) {
      bf16x8 ap;
      if (fcol < 8) ap = *(const bf16x8*)&psh[fcol * 224 + ks * 32 + g * 8];
      else { bf16x8 z = {}; ap = z; }
      bf16x8 bv = *(const bf16x8*)&vtsh[(w * 16 + fcol) * 224 + ks * 32 + g * 8];
      acc = __builtin_amdgcn_mfma_f32_16x16x32_bf16(ap, bv, acc, 0, 0, 0);
    }
    if (g < 2) {
#pragma unroll
      for (int r = 0; r < 4; ++r) {
        int i = i0 + g * 4 + r;
        o[(size_t)(bb * KK + i) * DDIM + h * DH + w * 16 + fcol] = (bf16_t)acc[r];
      }
    }
  }
}

// ------ fused tail v4: BM=16, grid 100, (512,6) ----------------------------
__global__ __launch_bounds__(512, 6) void tail_fused(const bf16_t* __restrict__ obufbf,
    const bf16_t* __restrict__ oWt, const float* __restrict__ ob,
    const float* __restrict__ ln1g, const float* __restrict__ ln1b,
    const bf16_t* __restrict__ W1t, const float* __restrict__ b1,
    const bf16_t* __restrict__ W2t, const float* __restrict__ b2,
    const float* __restrict__ ln2g, const float* __restrict__ ln2b,
    float* __restrict__ btok, bf16_t* __restrict__ btokbf,
    const bf16_t* __restrict__ nqWt, const float* __restrict__ nqb,
    const bf16_t* __restrict__ nkWt, const float* __restrict__ nkb,
    const bf16_t* __restrict__ nvWt, const float* __restrict__ nvb,
    bf16_t* __restrict__ nqo, bf16_t* __restrict__ nko, bf16_t* __restrict__ nvo) {
  __shared__ __align__(16) bf16_t Alds[16 * 16 * 8];   // 4KB
  __shared__ __align__(16) bf16_t Blds[128 * 16 * 8];  // 32KB streamed
  __shared__ __align__(16) bf16_t Hlds[16 * 512];      // 16KB hidden
  __shared__ float lnredS[16][8], lnredQ[16][8];       // 1KB cross-wave LN
  const int tid = threadIdx.x, m0 = blockIdx.x * 16;
  const int w = tid >> 6, lane = tid & 63, fcol = lane & 15, g = lane >> 4;
  const int cb = w * 16;                    // this wave's 16-col slice
  const int arow = fcol;                    // A row within the 16-row tile
  if (tid < 256) {
    int row = tid >> 4, kc = tid & 15;      // 16 rows * 16 kb
    uint4 d = *(const uint4*)(obufbf + (size_t)(m0 + row) * 128 + kc * 8);
    *(uint4*)&Alds[(row * 16 + (kc ^ (row & 7))) * 8] = d;
  }
#pragma unroll
  for (int it = 0; it < 4; ++it) {
    int u = tid + it * 512;                 // < 2048
    int col = u >> 4, kcb = u & 15;
    uint4 d = *(const uint4*)(oWt + (size_t)col * 128 + kcb * 8);
    *(uint4*)&Blds[(col * 16 + (kcb ^ (col & 7))) * 8] = d;
  }
  __syncthreads();
  // ---- oproj GEMM (per wave: 16 rows x 16 cols) ----
  f32x4 acc = {0.f, 0.f, 0.f, 0.f};
#pragma unroll
  for (int ks = 0; ks < 4; ++ks) {
    bf16x8 a = *(const bf16x8*)&Alds[(arow * 16 + ((ks * 4 + g) ^ (arow & 7))) * 8];
    const int bcol = cb + fcol;
    bf16x8 b = *(const bf16x8*)&Blds[(bcol * 16 + ((ks * 4 + g) ^ (bcol & 7))) * 8];
    acc = __builtin_amdgcn_mfma_f32_16x16x32_bf16(a, b, acc, 0, 0, 0);
  }
  // ---- +ob +residual, LN1 (cross-wave 8-slice combine) ----
  float lnr[4];
  {
    float s_[4], q_[4];
    const int col = cb + fcol;
    const float bv = ob[col];
#pragma unroll
    for (int r = 0; r < 4; ++r) {
      const int row = m0 + 4 * g + r;
      float val = acc[r] + bv + btok[(size_t)row * 128 + col];
      lnr[r] = val;
      s_[r] = val; q_[r] = val * val;
    }
#pragma unroll
    for (int m = 1; m <= 8; m <<= 1)
#pragma unroll
      for (int r = 0; r < 4; ++r) {
        s_[r] += __shfl_xor(s_[r], m); q_[r] += __shfl_xor(q_[r], m);
      }
    if (fcol == 0) {
#pragma unroll
      for (int r = 0; r < 4; ++r) {
        lnredS[4 * g + r][w] = s_[r];
        lnredQ[4 * g + r][w] = q_[r];
      }
    }
    __syncthreads();
    float mean[4], rs[4];
#pragma unroll
    for (int r = 0; r < 4; ++r) {
      const int rl = 4 * g + r;
      float S = 0.f, Q = 0.f;
#pragma unroll
      for (int ww = 0; ww < 8; ++ww) { S += lnredS[rl][ww]; Q += lnredQ[rl][ww]; }
      mean[r] = S * (1.f / 128.f);
      rs[r] = rsqrtf(Q * (1.f / 128.f) - mean[r] * mean[r] + 1e-5f);
    }
    const float gv = ln1g[col], bv2 = ln1b[col];
#pragma unroll
    for (int r = 0; r < 4; ++r) {
      float v2 = (lnr[r] - mean[r]) * rs[r] * gv + bv2;
      lnr[r] = v2;
      const int rowL = 4 * g + r;
      Alds[(rowL * 16 + ((col >> 3) ^ (rowL & 7))) * 8 + (col & 7)] = (bf16_t)v2;
    }
  }
  __syncthreads();
  // ---- FFN phase 1: Hlds = gelu(ln1 @ W1 + b1) ----
  for (int nc = 0; nc < 4; ++nc) {
#pragma unroll
    for (int it = 0; it < 4; ++it) {
      int u = tid + it * 512;
      int col = u >> 4, kcb = u & 15;
      uint4 d = *(const uint4*)(W1t + (size_t)(nc * 128 + col) * 128 + kcb * 8);
      *(uint4*)&Blds[(col * 16 + (kcb ^ (col & 7))) * 8] = d;
    }
    __syncthreads();
    f32x4 a1 = {0.f, 0.f, 0.f, 0.f};
#pragma unroll
    for (int ks = 0; ks < 4; ++ks) {
      bf16x8 a = *(const bf16x8*)&Alds[(arow * 16 + ((ks * 4 + g) ^ (arow & 7))) * 8];
      const int bcol = cb + fcol;
      bf16x8 b = *(const bf16x8*)&Blds[(bcol * 16 + ((ks * 4 + g) ^ (bcol & 7))) * 8];
      a1 = __builtin_amdgcn_mfma_f32_16x16x32_bf16(a, b, a1, 0, 0, 0);
    }
    {
      const int c = nc * 128 + cb + fcol;
      const float bv = b1[c];
      const int kb = c >> 3, within = c & 7;
#pragma unroll
      for (int r = 0; r < 4; ++r) {
        const int row = 4 * g + r;
        const int kbs = kb ^ (row & 7);
        Hlds[row * 512 + kbs * 8 + within] = (bf16_t)egelu(a1[r] + bv);
      }
    }
    __syncthreads();
  }
  // ---- FFN phase 2: acc2 = H @ W2 ----
  f32x4 acc2 = {0.f, 0.f, 0.f, 0.f};
  for (int kc = 0; kc < 4; ++kc) {
#pragma unroll
    for (int it = 0; it < 4; ++it) {
      int u = tid + it * 512;
      int col = u >> 4, kcb = u & 15;
      uint4 d = *(const uint4*)(W2t + (size_t)col * 512 + kc * 128 + kcb * 8);
      *(uint4*)&Blds[(col * 16 + (kcb ^ (col & 7))) * 8] = d;
    }
    __syncthreads();
#pragma unroll
    for (int ks = 0; ks < 4; ++ks) {
      const int kb = kc * 16 + ks * 4 + g;
      const int kbs = kb ^ (arow & 7);
      bf16x8 a = *(const bf16x8*)&Hlds[arow * 512 + kbs * 8];
      const int bcol = cb + fcol;
      bf16x8 b = *(const bf16x8*)&Blds[(bcol * 16 + ((ks * 4 + g) ^ (bcol & 7))) * 8];
      acc2 = __builtin_amdgcn_mfma_f32_16x16x32_bf16(a, b, acc2, 0, 0, 0);
    }
    __syncthreads();
  }
  // ---- +b2 +ln1-residual, LN2 -> btok/btokbf (+ Alds for next qkv) ----
  {
    float s_[4], q_[4];
    const int col = cb + fcol;
    const float bv = b2[col];
#pragma unroll
    for (int r = 0; r < 4; ++r) {
      float val = acc2[r] + bv + lnr[r];
      lnr[r] = val;
      s_[r] = val; q_[r] = val * val;
    }
#pragma unroll
    for (int m = 1; m <= 8; m <<= 1)
#pragma unroll
      for (int r = 0; r < 4; ++r) {
        s_[r] += __shfl_xor(s_[r], m); q_[r] += __shfl_xor(q_[r], m);
      }
    if (fcol == 0) {
#pragma unroll
      for (int r = 0; r < 4; ++r) {
        lnredS[4 * g + r][w] = s_[r];
        lnredQ[4 * g + r][w] = q_[r];
      }
    }
    __syncthreads();
    float mean[4], rs[4];
#pragma unroll
    for (int r = 0; r < 4; ++r) {
      const int rl = 4 * g + r;
      float S = 0.f, Q = 0.f;
#pragma unroll
      for (int ww = 0; ww < 8; ++ww) { S += lnredS[rl][ww]; Q += lnredQ[rl][ww]; }
      mean[r] = S * (1.f / 128.f);
      rs[r] = rsqrtf(Q * (1.f / 128.f) - mean[r] * mean[r] + 1e-5f);
    }
    const float gv = ln2g[col], bv2 = ln2b[col];
#pragma unroll
    for (int r = 0; r < 4; ++r) {
      const int row = m0 + 4 * g + r;
      float oval = (lnr[r] - mean[r]) * rs[r] * gv + bv2;
      btok[(size_t)row * 128 + col] = oval;
      btokbf[(size_t)row * 128 + col] = (bf16_t)oval;
      if (nqWt) {
        const int rowL = 4 * g + r;
        Alds[(rowL * 16 + ((col >> 3) ^ (rowL & 7))) * 8 + (col & 7)] = (bf16_t)oval;
      }
    }
  }
  // ---- next-layer qkv from LN2 output (Alds) ----
  if (nqWt) {
    __syncthreads();
    const bf16_t* Ws[3] = {nqWt, nkWt, nvWt};
    const float* bs[3] = {nqb, nkb, nvb};
    bf16_t* Cs[3] = {nqo, nko, nvo};
    for (int zz = 0; zz < 3; ++zz) {
      const bf16_t* Wt = Ws[zz];
#pragma unroll
      for (int it = 0; it < 4; ++it) {
        int u = tid + it * 512;
        int col = u >> 4, kcb = u & 15;
        uint4 d = *(const uint4*)(Wt + (size_t)col * 128 + kcb * 8);
        *(uint4*)&Blds[(col * 16 + (kcb ^ (col & 7))) * 8] = d;
      }
      __syncthreads();
      f32x4 aq = {0.f, 0.f, 0.f, 0.f};
#pragma unroll
      for (int ks = 0; ks < 4; ++ks) {
        bf16x8 a = *(const bf16x8*)&Alds[(arow * 16 + ((ks * 4 + g) ^ (arow & 7))) * 8];
        const int bcol = cb + fcol;
        bf16x8 b = *(const bf16x8*)&Blds[(bcol * 16 + ((ks * 4 + g) ^ (bcol & 7))) * 8];
        aq = __builtin_amdgcn_mfma_f32_16x16x32_bf16(a, b, aq, 0, 0, 0);
      }
      const float bv = bs[zz][cb + fcol];
      bf16_t* C = Cs[zz];
#pragma unroll
      for (int r = 0; r < 4; ++r) {
        const int row = m0 + 4 * g + r;
        C[(size_t)row * 128 + cb + fcol] = (bf16_t)(aq[r] + bv);
      }
      __syncthreads();
    }
  }
}

// ---------------- fused readout v2: 1024 threads ---------------------------
__global__ __launch_bounds__(1024) void readout_fused(const float* __restrict__ B,
    const bf16_t* __restrict__ Bbf, const float* __restrict__ slots,
    const float* __restrict__ task_q, const float* __restrict__ memg,
    const float* __restrict__ membt, const float* __restrict__ headW,
    const float* __restrict__ headb, float* __restrict__ out) {
  __shared__ __align__(16) bf16_t Ssh[64 * 16 * 8];   // 16KB
  __shared__ __align__(16) bf16_t Bsh[208 * 128];     // 53KB
  __shared__ float wcsh[4][208];
  __shared__ __align__(16) float tq[128];
  __shared__ float ras[KK];
  __shared__ float wc[208];
  __shared__ float red1[4], red2[4];
  __shared__ float hv2[1024], mv2[1024];              // 8KB
  __shared__ float hv[128], mv[128], rv[128];
  __shared__ float stats[2];
  const int b = blockIdx.x, tid = threadIdx.x;
  const int w = tid >> 6, lane = tid & 63, fcol = lane & 15, g = lane >> 4;
  {
    int u = tid;                            // 1024 = 64 rows * 16 kb
    int row = u >> 4, kb = u & 15;
    const float* sp = slots + (size_t)row * 128 + kb * 8;
    bf16_t tmp[8];
#pragma unroll
    for (int e = 0; e < 8; ++e) tmp[e] = (bf16_t)sp[e];
    *(uint4*)&Ssh[(row * 16 + (kb ^ (row & 7))) * 8] = *(uint4*)tmp;
  }
#pragma unroll
  for (int it = 0; it < 4; ++it) {
    int u = tid + it * 1024;                // < 3328
    if (u < 3328) {
      int c = u >> 4, kb = u & 15;
      uint4 d = {0u, 0u, 0u, 0u};
      if (c < KK) d = *(const uint4*)(Bbf + (size_t)(b * KK + c) * 128 + kb * 8);
      *(uint4*)&Bsh[(c * 16 + (kb ^ (c & 7))) * 8] = d;
    }
  }
  if (tid < 128) tq[tid] = task_q[tid];
  __syncthreads();
  // ---- slot scores via MFMA (waves 0..3) ----
  if (w < 4) {
    bf16x8 afr[4];
#pragma unroll
    for (int ks = 0; ks < 4; ++ks) {
      const int arow = 16 * w + fcol;
      afr[ks] = *(const bf16x8*)&Ssh[(arow * 16 + ((ks * 4 + g) ^ (arow & 7))) * 8];
    }
    f32x4 acc[13];
#pragma unroll
    for (int ct = 0; ct < 13; ++ct) {
      acc[ct] = (f32x4){0.f, 0.f, 0.f, 0.f};
#pragma unroll
      for (int ks = 0; ks < 4; ++ks) {
        const int bcol = ct * 16 + fcol;
        bf16x8 bb = *(const bf16x8*)&Bsh[(bcol * 16 + ((ks * 4 + g) ^ (bcol & 7))) * 8];
        acc[ct] = __builtin_amdgcn_mfma_f32_16x16x32_bf16(afr[ks], bb, acc[ct], 0, 0, 0);
      }
    }
    if (fcol >= 8) { acc[12][0] = -1e30f; acc[12][1] = -1e30f; acc[12][2] = -1e30f; acc[12][3] = -1e30f; }
    const float s2 = 0.08838834764831845f * 1.4426950408889634f;
    float wcp[13];
#pragma unroll
    for (int ct = 0; ct < 13; ++ct) wcp[ct] = 0.f;
#pragma unroll
    for (int r = 0; r < 4; ++r) {
      float m = acc[0][r];
#pragma unroll
      for (int ct = 1; ct < 13; ++ct) m = fmaxf(m, acc[ct][r]);
      m = fmaxf(m, __shfl_xor(m, 1));
      m = fmaxf(m, __shfl_xor(m, 2));
      m = fmaxf(m, __shfl_xor(m, 4));
      m = fmaxf(m, __shfl_xor(m, 8));
      float l = 0.f;
      float p[13];
#pragma unroll
      for (int ct = 0; ct < 13; ++ct) {
        p[ct] = fastexp2((acc[ct][r] - m) * s2);
        l += p[ct];
      }
      l += __shfl_xor(l, 1);
      l += __shfl_xor(l, 2);
      l += __shfl_xor(l, 4);
      l += __shfl_xor(l, 8);
      const float inv = fastrcp(l);
#pragma unroll
      for (int ct = 0; ct < 13; ++ct) wcp[ct] = fmaf(p[ct], inv, wcp[ct]);
    }
#pragma unroll
    for (int ct = 0; ct < 13; ++ct) {
      wcp[ct] += __shfl_xor(wcp[ct], 16);
      wcp[ct] += __shfl_xor(wcp[ct], 32);
      if (g == 0) wcsh[w][ct * 16 + fcol] = wcp[ct];
    }
  }
  // ---- ra = softmax(b . task_q / sqrt(128)) on threads 0..255 ----
  if (tid < 256) {
    float sc = -1e30f;
    if (tid < KK) {
      const float* br = B + (size_t)(b * KK + tid) * DDIM;
      float a = 0.f;
#pragma unroll
      for (int d4 = 0; d4 < 32; d4++) {
        float4 bb = *(const float4*)(br + d4 * 4);
        float4 ss = *(const float4*)(tq + d4 * 4);
        a += bb.x * ss.x + bb.y * ss.y + bb.z * ss.z + bb.w * ss.w;
      }
      sc = a * 0.08838834764831845f;
    }
    float mx = sc;
#pragma unroll
    for (int m = 1; m <= 32; m <<= 1) mx = fmaxf(mx, __shfl_xor(mx, m));
    if (lane == 0) red1[w] = mx;
    __threadfence_block();
    // combine across 4 waves after a block barrier below; store sc for later
    ras[tid < KK ? tid : (KK - 1)] = 0.f;   // placeholder init (overwritten)
    hv2[tid] = sc;                          // stash score in scratch
  }
  __syncthreads();
  if (tid < 256) {
    float sc = hv2[tid];
    float mx = fmaxf(fmaxf(red1[0], red1[1]), fmaxf(red1[2], red1[3]));
    float p = (tid < KK) ? __expf(sc - mx) : 0.f;
    float sm = p;
#pragma unroll
    for (int m = 1; m <= 32; m <<= 1) sm += __shfl_xor(sm, m);
    if (lane == 0) red2[w] = sm;
    hv2[tid] = p;                           // stash numerator
  }
  __syncthreads();
  if (tid < KK) {
    float sm = red2[0] + red2[1] + red2[2] + red2[3];
    ras[tid] = hv2[tid] / sm;
  }
  if (tid < 208)
    wc[tid] = (wcsh[0][tid] + wcsh[1][tid] + wcsh[2][tid] + wcsh[3][tid]) * (1.f / 64.f);
  __syncthreads();
  // ---- hv = ras @ B ; mv = wc @ B (8-way c-split) ----
  {
    const int d = tid & 127, oct = tid >> 7;   // 0..7
    float hd = 0.f, md = 0.f;
    const float* Bb = B + ((size_t)b * KK + oct * 25) * DDIM + d;
    const float* rp = ras + oct * 25;
    const float* wp = wc + oct * 25;
#pragma unroll 5
    for (int c = 0; c < 25; ++c) {
      float bv = Bb[(size_t)c * DDIM];
      hd = fmaf(rp[c], bv, hd);
      md = fmaf(wp[c], bv, md);
    }
    hv2[tid] = hd; mv2[tid] = md;
  }
  __syncthreads();
  if (tid < 128) {
    float hsum = 0.f, msum = 0.f;
#pragma unroll
    for (int o2 = 0; o2 < 8; ++o2) {
      hsum += hv2[tid + 128 * o2];
      msum += mv2[tid + 128 * o2];
    }
    hv[tid] = hsum; mv[tid] = msum;
  }
  __syncthreads();
  if (tid < 64) {
    float x0 = mv[tid], x1 = mv[tid + 64];
    float s = x0 + x1, qq = x0 * x0 + x1 * x1;
#pragma unroll
    for (int m = 1; m <= 32; m <<= 1) { s += __shfl_xor(s, m); qq += __shfl_xor(qq, m); }
    if (tid == 0) { stats[0] = s; stats[1] = qq; }
  }
  __syncthreads();
  float mean = stats[0] * (1.f / 128.f);
  float var = stats[1] * (1.f / 128.f) - mean * mean;
  float rs = rsqrtf(var + 1e-5f);
  if (tid < 128) rv[tid] = hv[tid] + (mv[tid] - mean) * rs * memg[tid] + membt[tid];
  __syncthreads();
  if (tid < OUTN) {
    float a = headb[tid];
    for (int dd = 0; dd < 128; dd++) a = fmaf(rv[dd], headW[dd * OUTN + tid], a);
    out[b * OUTN + tid] = a;
  }
}

// ---------------------------------------------------------------------------
extern "C" void kernel_launch(void* const* d_in, const int* in_sizes, int n_in,
                              void* d_out, int out_size, void* d_ws, size_t ws_size,
                              hipStream_t stream) {
  (void)in_sizes; (void)n_in; (void)out_size; (void)ws_size;
  const float* x        = (const float*)d_in[0];
  const float* role_emb = (const float*)d_in[1];
  const float* filler_w = (const float*)d_in[2];
  const float* qW = (const float*)d_in[3];
  const float* qb = (const float*)d_in[4];
  const float* kW = (const float*)d_in[5];
  const float* kb = (const float*)d_in[6];
  const float* vW = (const float*)d_in[7];
  const float* vb = (const float*)d_in[8];
  const float* oW = (const float*)d_in[9];
  const float* ob = (const float*)d_in[10];
  const float* relW1 = (const float*)d_in[11];
  const float* relb1 = (const float*)d_in[12];
  const float* relW2 = (const float*)d_in[13];
  const float* relb2 = (const float*)d_in[14];
  const float* ln1g = (const float*)d_in[15];
  const float* ln1b = (const float*)d_in[16];
  const float* ln2g = (const float*)d_in[17];
  const float* ln2b = (const float*)d_in[18];
  const float* fW1 = (const float*)d_in[19];
  const float* fb1 = (const float*)d_in[20];
  const float* fW2 = (const float*)d_in[21];
  const float* fb2 = (const float*)d_in[22];
  const float* slots = (const float*)d_in[23];
  const float* memg = (const float*)d_in[24];
  const float* memb = (const float*)d_in[25];
  const float* taskq = (const float*)d_in[26];
  const float* headW = (const float*)d_in[27];
  const float* headb = (const float*)d_in[28];
  float* out = (float*)d_out;
  (void)relb2;  // dropped: softmax shift-invariance

  // workspace layout (float-slot offsets; all 16B aligned)
  float* fws  = (float*)d_ws;
  float*  btok   = fws;                       // 204800 f
  bf16_t* btokbf = (bf16_t*)(fws + 204800);   // 204800 bf16
  bf16_t* qbf    = (bf16_t*)(fws + 307200);   // 204800 bf16
  bf16_t* kbf    = (bf16_t*)(fws + 409600);   // 204800 bf16
  bf16_t* vbf    = (bf16_t*)(fws + 512000);   // 204800 bf16
  bf16_t* obufbf = (bf16_t*)(fws + 614400);   // 204800 bf16
  bf16_t* wtb    = (bf16_t*)(fws + 716800);   // 589824 bf16 (end ~4.0MB)
  bf16_t* qWt = wtb, *kWt = wtb + 49152, *vWt = wtb + 98304, *oWt = wtb + 147456;
  bf16_t* fW1t = wtb + 196608, *fW2t = wtb + 393216;

  prep_kernel<<<152, 256, 0, stream>>>(qW, kW, vW, oW, fW1, fW2, wtb,
      x, role_emb, filler_w, btok, btokbf);
  qkv_mfma<<<dim3(50, 3), 256, 0, stream>>>(btokbf,
      qWt, qb, kWt, kb, vWt, vb, qbf, kbf, vbf);
  for (int l = 0; l < LLAY; l++) {
    rel_attn_mfma<<<dim3(25, 32), 512, 0, stream>>>(qbf, kbf, vbf,
        relW1 + l * 3072, relb1 + l * 32, relW2 + l * 32, obufbf);
    const bool nx = (l + 1 < LLAY);
    tail_fused<<<100, 512, 0, stream>>>(obufbf, oWt + l * 16384, ob + l * 128,
        ln1g + l * 128, ln1b + l * 128, fW1t + l * 65536, fb1 + l * 512,
        fW2t + l * 65536, fb2 + l * 128, ln2g + l * 128, ln2b + l * 128,
        btok, btokbf,
        nx ? qWt + (l + 1) * 16384 : (const bf16_t*)nullptr,
        nx ? qb + (l + 1) * 128 : (const float*)nullptr,
        nx ? kWt + (l + 1) * 16384 : (const bf16_t*)nullptr,
        nx ? kb + (l + 1) * 128 : (const float*)nullptr,
        nx ? vWt + (l + 1) * 16384 : (const bf16_t*)nullptr,
        nx ? vb + (l + 1) * 128 : (const float*)nullptr,
        qbf, kbf, vbf);
  }
  readout_fused<<<8, 1024, 0, stream>>>(btok, btokbf, slots, taskq,
      memg, memb, headW, headb, out);
}

// Round 14
// 209.183 us; speedup vs baseline: 1.4011x; 1.4011x over previous
//
#include <hip/hip_runtime.h>
#include <math.h>

#define BQ 8
#define CC 2048
#define DDIM 128
#define LLAY 3
#define HH 4
#define KK 200
#define SSLOT 64
#define OUTN 24
#define DH 32

typedef __bf16 bf16_t;
typedef __bf16 bf16x8 __attribute__((ext_vector_type(8)));
typedef float f32x4 __attribute__((ext_vector_type(4)));

__device__ __forceinline__ float fastrcp(float x) {
#if __has_builtin(__builtin_amdgcn_rcpf)
  return __builtin_amdgcn_rcpf(x);
#else
  return 1.0f / x;
#endif
}
__device__ __forceinline__ float fastexp2(float x) {
#if __has_builtin(__builtin_amdgcn_exp2f)
  return __builtin_amdgcn_exp2f(x);
#else
  return exp2f(x);
#endif
}
// gelu tanh-approx: x - x/(1+e^y); inf/underflow give exact limits
__device__ __forceinline__ float fgelu2(float x) {
  float s = x * x;
  float inner = fmaf(0.044715f * s, x, x);
  float e = fastexp2(inner * 2.302118610509359f);  // 2*0.79788456*log2(e)
  float r = fastrcp(1.f + e);
  return fmaf(-x, r, x);
}
__device__ __forceinline__ float egelu(float x) {
  return 0.5f * x * (1.f + erff(x * 0.7071067811865476f));
}

// ---------------- prep: wconv (blocks 0..143) + topk+bind (144..151) -------
__global__ __launch_bounds__(256) void prep_kernel(
    const float* __restrict__ qW, const float* __restrict__ kW,
    const float* __restrict__ vW, const float* __restrict__ oW,
    const float* __restrict__ fW1, const float* __restrict__ fW2,
    bf16_t* __restrict__ wtb,
    const float* __restrict__ x, const float* __restrict__ role_emb,
    const float* __restrict__ fw, float* __restrict__ btok,
    bf16_t* __restrict__ btokbf) {
  __shared__ float Ts[64][65];
  __shared__ float svals[KK];
  __shared__ int sidx[KK];
  __shared__ int redbuf[2][4];
  __shared__ int cnt;
  const int blk = blockIdx.x, tid = threadIdx.x;
  if (blk < 144) {
    const int t = blk;
    const float* src; bf16_t* dst; int N, K, k0, n0;
    if (t < 48) {
      int which = t / 12, rem = t % 12;
      int l = rem >> 2, tt = rem & 3;
      N = 128; K = 128; k0 = (tt >> 1) * 64; n0 = (tt & 1) * 64;
      src = (which == 0 ? qW : which == 1 ? kW : which == 2 ? vW : oW) + l * 16384;
      dst = wtb + which * 49152 + l * 16384;
    } else if (t < 96) {
      int t2 = t - 48, l = t2 >> 4, tt = t2 & 15;
      N = 512; K = 128; k0 = (tt >> 3) * 64; n0 = (tt & 7) * 64;
      src = fW1 + l * 65536;
      dst = wtb + 196608 + l * 65536;
    } else {
      int t3 = t - 96, l = t3 >> 4, tt = t3 & 15;
      N = 128; K = 512; k0 = (tt >> 1) * 64; n0 = (tt & 1) * 64;
      src = fW2 + l * 65536;
      dst = wtb + 393216 + l * 65536;
    }
#pragma unroll
    for (int i = 0; i < 16; ++i) {
      int u = tid + i * 256;
      int r = u >> 6, c = u & 63;
      Ts[r][c] = src[(size_t)(k0 + r) * N + n0 + c];
    }
    __syncthreads();
#pragma unroll
    for (int i = 0; i < 16; ++i) {
      int u = tid + i * 256;
      int rn = u >> 6, ck = u & 63;
      dst[(size_t)(n0 + rn) * K + k0 + ck] = (bf16_t)Ts[ck][rn];
    }
    return;
  }
  // ---- top-k + bind for batch b ----
  const int b = blk - 144;
  const int w = tid >> 6, lane = tid & 63;
  float xv[8]; unsigned xb[8];
#pragma unroll
  for (int t = 0; t < 8; t++) {
    float v = x[b * CC + t * 256 + tid];
    xv[t] = v;
    xb[t] = __float_as_uint(v);
  }
  unsigned lo = 0u, hi = 0x7f800000u;
  int itn = 0;
  while (lo < hi) {                          // 1 barrier/iter (dbuf + ballot)
    unsigned mid = (lo + hi) >> 1;
    int c = 0;
#pragma unroll
    for (int t = 0; t < 8; t++) c += __popcll(__ballot(xb[t] > mid));
    if (lane == 0) redbuf[itn & 1][w] = c;
    __syncthreads();
    int ct = redbuf[itn & 1][0] + redbuf[itn & 1][1] +
             redbuf[itn & 1][2] + redbuf[itn & 1][3];
    if (ct >= KK) lo = mid + 1; else hi = mid;
    ++itn;
  }
  const unsigned thr = lo;
  if (tid == 0) cnt = 0;
  __syncthreads();
#pragma unroll
  for (int t = 0; t < 8; t++) {
    if (xb[t] > thr) {
      int p = atomicAdd(&cnt, 1);
      svals[p] = log1pf(xv[t]);
      sidx[p] = t * 256 + tid;
    }
  }
  __syncthreads();
#pragma unroll
  for (int t = 0; t < 8; t++) {
    if (xb[t] == thr) {
      int p = atomicAdd(&cnt, 1);
      if (p < KK) {
        svals[p] = log1pf(xv[t]);
        sidx[p] = t * 256 + tid;
      }
    }
  }
  __syncthreads();
  for (int u = tid; u < KK * DDIM; u += 256) {
    int dd = u & 127, t = u >> 7;
    float v = svals[t];
    float fill = egelu(v * fw[dd]);
    float val = role_emb[(size_t)sidx[t] * DDIM + dd] * fill;
    btok[(size_t)b * KK * DDIM + u] = val;
    btokbf[(size_t)b * KK * DDIM + u] = (bf16_t)val;
  }
}

// ---------------- qkv (layer 0 only): BM=32, grid (50,3); outputs bf16 -----
__global__ __launch_bounds__(256) void qkv_mfma(const bf16_t* __restrict__ A,
    const bf16_t* __restrict__ qWt, const float* __restrict__ qb,
    const bf16_t* __restrict__ kWt, const float* __restrict__ kb,
    const bf16_t* __restrict__ vWt, const float* __restrict__ vb,
    bf16_t* __restrict__ qo, bf16_t* __restrict__ ko, bf16_t* __restrict__ vo) {
  __shared__ __align__(16) bf16_t Alds[32 * 16 * 8];
  __shared__ __align__(16) bf16_t Blds[128 * 16 * 8];
  const int tid = threadIdx.x, m0 = blockIdx.x * 32, z = blockIdx.y;
  const bf16_t* Wt; const float* bias; bf16_t* C;
  if (z == 0) { Wt = qWt; bias = qb; C = qo; }
  else if (z == 1) { Wt = kWt; bias = kb; C = ko; }
  else { Wt = vWt; bias = vb; C = vo; }
#pragma unroll
  for (int it = 0; it < 2; ++it) {
    int u = tid + it * 256;                 // < 512
    int row = u >> 4, kc = u & 15;
    uint4 d = *(const uint4*)(A + (size_t)(m0 + row) * 128 + kc * 8);
    *(uint4*)&Alds[(row * 16 + (kc ^ (row & 7))) * 8] = d;
  }
#pragma unroll
  for (int it = 0; it < 8; ++it) {
    int u = tid + it * 256;
    int col = u >> 4, kcb = u & 15;
    uint4 d = *(const uint4*)(Wt + (size_t)col * 128 + kcb * 8);
    *(uint4*)&Blds[(col * 16 + (kcb ^ (col & 7))) * 8] = d;
  }
  __syncthreads();
  const int w = tid >> 6, lane = tid & 63, fcol = lane & 15, g = lane >> 4;
  const int wr = w & 1, wn = w >> 1;
  f32x4 acc[4];
#pragma unroll
  for (int ni = 0; ni < 4; ++ni) acc[ni] = (f32x4){0.f, 0.f, 0.f, 0.f};
#pragma unroll
  for (int ks = 0; ks < 4; ++ks) {
    const int arow = 16 * wr + fcol;
    bf16x8 a = *(const bf16x8*)&Alds[(arow * 16 + ((ks * 4 + g) ^ (arow & 7))) * 8];
#pragma unroll
    for (int ni = 0; ni < 4; ++ni) {
      const int bcol = wn * 64 + ni * 16 + fcol;
      bf16x8 b = *(const bf16x8*)&Blds[(bcol * 16 + ((ks * 4 + g) ^ (bcol & 7))) * 8];
      acc[ni] = __builtin_amdgcn_mfma_f32_16x16x32_bf16(a, b, acc[ni], 0, 0, 0);
    }
  }
#pragma unroll
  for (int ni = 0; ni < 4; ++ni) {
    const int col = wn * 64 + ni * 16 + fcol;
    const float bv = bias[col];
#pragma unroll
    for (int r = 0; r < 4; ++r) {
      const int row = m0 + 16 * wr + 4 * g + r;
      C[(size_t)row * 128 + col] = (bf16_t)(acc[ni][r] + bv);
    }
  }
}

// ---------------- fused relational attention v12: (512,4) proven profile ---
__global__ __launch_bounds__(512, 4) void rel_attn_mfma(
    const bf16_t* __restrict__ qbf, const bf16_t* __restrict__ kbf,
    const bf16_t* __restrict__ vbf,
    const float* __restrict__ W1g, const float* __restrict__ b1g,
    const float* __restrict__ w2p, bf16_t* __restrict__ o) {
  __shared__ __align__(16) bf16_t ksh[208 * 32];   // 13312 B, 16B-block swizz
  __shared__ __align__(16) bf16_t vtsh[32 * 224];  // 14336 B, V^T [f'][j]
  __shared__ __align__(16) bf16_t psh[8 * 224];    // 3584 B, P [i][j]
  __shared__ __align__(16) bf16_t W1ki[32 * 66];   // 4224 B (k,i) pairs, +2 pad
  __shared__ __align__(16) bf16_t qsh[8 * 32];     // 512 B
  __shared__ __align__(16) bf16_t qtshb[8 * 32];   // 512 B    (sum 36480)
  const int tid = threadIdx.x;
  const int bh = blockIdx.y, bb = bh >> 2, h = bh & 3;
  const int i0 = blockIdx.x * 8;
  const bf16_t* kgb = kbf + (size_t)(bb * KK) * DDIM + h * DH;
  const bf16_t* vgb = vbf + (size_t)(bb * KK) * DDIM + h * DH;
  const bf16_t* qgb = qbf + (size_t)(bb * KK) * DDIM + h * DH;
  // ---- stage K (16B units, swizzled) ----
#pragma unroll
  for (int it = 0; it < 2; ++it) {
    int u = tid + it * 512;                 // < 832
    if (u < 832) {
      int j = u >> 2, bi = u & 3;
      uint4 d = {0u, 0u, 0u, 0u};
      if (j < KK) d = *(const uint4*)(kgb + (size_t)j * DDIM + bi * 8);
      *(uint4*)&ksh[j * 32 + (bi ^ ((j >> 1) & 3)) * 8] = d;
    }
  }
  // ---- stage V^T (stride 224, cols >=200 zero) ----
#pragma unroll
  for (int it = 0; it < 7; ++it) {
    int u = tid + it * 512;                 // < 3328 = 104 j-pairs * 32 f
    if (u < 3328) {
      int jp = u >> 5, f = u & 31;
      int j0 = jp * 2;
      bf16_t a0 = (j0 < KK) ? vgb[(size_t)j0 * DDIM + f] : (bf16_t)0.f;
      bf16_t a1 = (j0 + 1 < KK) ? vgb[(size_t)(j0 + 1) * DDIM + f] : (bf16_t)0.f;
      union { bf16_t h2[2]; unsigned uu; } pk;
      pk.h2[0] = a0; pk.h2[1] = a1;
      *(unsigned*)&vtsh[f * 224 + j0] = pk.uu;
    }
  }
  if (tid < 256) {                          // vtsh pad cols 208..223
    int f = tid >> 3, cp = tid & 7;
    *(unsigned*)&vtsh[f * 224 + 208 + cp * 2] = 0u;
  }
  if (tid < 64) {                           // psh pad cols 208..223
    int r = tid >> 3, cp = tid & 7;
    *(unsigned*)&psh[r * 224 + 208 + cp * 2] = 0u;
  }
  // ---- stage W1ki (bf16, stride 66) ----
#pragma unroll
  for (int it = 0; it < 4; ++it) {
    int u = tid + it * 512;                 // < 2048
    int sel = u & 1, f = (u >> 1) & 31, e = u >> 6;
    W1ki[e * 66 + f * 2 + sel] = (bf16_t)W1g[(32 + sel * 32 + e) * 32 + f];
  }
  // ---- stage q (bf16) ----
  if (tid < 128) {
    int il = tid >> 4, ep = tid & 15;
    *(unsigned*)&qsh[il * 32 + ep * 2] =
        *(const unsigned*)(qgb + (size_t)(i0 + il) * DDIM + ep * 2);
  }
  __syncthreads();
  // ---- qtv = q @ W1q + b1 (W1q from global; L2-hot) ----
  if (tid < 256) {
    int il = tid >> 5, f = tid & 31;
    float a = b1g[f];
#pragma unroll
    for (int e = 0; e < 32; ++e)
      a = fmaf((float)qsh[il * 32 + e], W1g[e * 32 + f], a);
    qtshb[il * 32 + f] = (bf16_t)a;
  }
  __syncthreads();
  const int w = tid >> 6, lane = tid & 63;
  const int fcol = lane & 15, g = lane >> 4;
  const float w2c = 0.17677669529663687f * 1.4426950408889634f;
  float4 w2a = *(const float4*)(w2p + 4 * g);
  float4 w2b = *(const float4*)(w2p + 16 + 4 * g);
  w2a.x *= w2c; w2a.y *= w2c; w2a.z *= w2c; w2a.w *= w2c;
  w2b.x *= w2c; w2b.y *= w2c; w2b.z *= w2c; w2b.w *= w2c;
  // ---- score phase: one query per wave (il = w) ----
  {
    const int il = w;
    bf16x8 qv8 = *(const bf16x8*)&qsh[il * 32 + g * 8];
    bf16x8 bw0, bw1;
#pragma unroll
    for (int e8 = 0; e8 < 8; ++e8) {
      int e = g * 8 + e8;
      float qe = (float)qv8[e8];
      union { unsigned u; bf16_t h[2]; } k0_, k1_;
      k0_.u = *(const unsigned*)&W1ki[e * 66 + fcol * 2];
      k1_.u = *(const unsigned*)&W1ki[e * 66 + (fcol + 16) * 2];
      bw0[e8] = (bf16_t)fmaf(qe, (float)k0_.h[1], (float)k0_.h[0]);
      bw1[e8] = (bf16_t)fmaf(qe, (float)k1_.h[1], (float)k1_.h[0]);
    }
    const bf16_t* qtp = &qtshb[il * 32];
    const f32x4 cin0 = {(float)qtp[4 * g + 0], (float)qtp[4 * g + 1],
                        (float)qtp[4 * g + 2], (float)qtp[4 * g + 3]};
    const f32x4 cin1 = {(float)qtp[16 + 4 * g + 0], (float)qtp[16 + 4 * g + 1],
                        (float)qtp[16 + 4 * g + 2], (float)qtp[16 + 4 * g + 3]};
    float s[13];
#pragma unroll
    for (int jt = 0; jt < 13; ++jt) {
      int j = jt * 16 + fcol;
      bf16x8 af = *(const bf16x8*)&ksh[j * 32 + (g ^ ((j >> 1) & 3)) * 8];
      f32x4 acc0 = __builtin_amdgcn_mfma_f32_16x16x32_bf16(bw0, af, cin0, 0, 0, 0);
      f32x4 acc1 = __builtin_amdgcn_mfma_f32_16x16x32_bf16(bw1, af, cin1, 0, 0, 0);
      float t0 = fgelu2(acc0[0]) * w2a.x;
      t0 = fmaf(fgelu2(acc0[1]), w2a.y, t0);
      float t1 = fgelu2(acc0[2]) * w2a.z;
      t1 = fmaf(fgelu2(acc0[3]), w2a.w, t1);
      float t2 = fgelu2(acc1[0]) * w2b.x;
      t2 = fmaf(fgelu2(acc1[1]), w2b.y, t2);
      float t3 = fgelu2(acc1[2]) * w2b.z;
      t3 = fmaf(fgelu2(acc1[3]), w2b.w, t3);
      float t = (t0 + t1) + (t2 + t3);
      t += __shfl_xor(t, 16);
      t += __shfl_xor(t, 32);
      s[jt] = t;
    }
    if (fcol >= 8) s[12] = -1e30f;          // mask j >= 200
    float m = s[0];
#pragma unroll
    for (int jt = 1; jt < 13; ++jt) m = fmaxf(m, s[jt]);
    m = fmaxf(m, __shfl_xor(m, 1));
    m = fmaxf(m, __shfl_xor(m, 2));
    m = fmaxf(m, __shfl_xor(m, 4));
    m = fmaxf(m, __shfl_xor(m, 8));
    float l = 0.f;
#pragma unroll
    for (int jt = 0; jt < 13; ++jt) {
      float p = fastexp2(s[jt] - m);
      s[jt] = p;
      l += p;
    }
    l += __shfl_xor(l, 1);
    l += __shfl_xor(l, 2);
    l += __shfl_xor(l, 4);
    l += __shfl_xor(l, 8);
    const float inv = fastrcp(l);
    if (g == 0) {
#pragma unroll
      for (int jt = 0; jt < 13; ++jt)
        psh[il * 224 + jt * 16 + fcol] = (bf16_t)(s[jt] * inv);
    }
  }
  __syncthreads();
  // ---- PV (waves 0,1) ----
  if (w < 2) {
    f32x4 acc = {0.f, 0.f, 0.f, 0.f};
#pragma unroll
    for (int ks = 0; ks < 7; ++ks) {
      bf16x8 ap;
      if (fcol < 8) ap = *(const bf16x8*)&psh[fcol * 224 + ks * 32 + g * 8];
      else { bf16x8 z = {}; ap = z; }
      bf16x8 bv = *(const bf16x8*)&vtsh[(w * 16 + fcol) * 224 + ks * 32 + g * 8];
      acc = __builtin_amdgcn_mfma_f32_16x16x32_bf16(ap, bv, acc, 0, 0, 0);
    }
    if (g < 2) {
#pragma unroll
      for (int r = 0; r < 4; ++r) {
        int i = i0 + g * 4 + r;
        o[(size_t)(bb * KK + i) * DDIM + h * DH + w * 16 + fcol] = (bf16_t)acc[r];
      }
    }
  }
}

// ------ fused tail v4: BM=16, grid 100, (512,6) ----------------------------
__global__ __launch_bounds__(512, 6) void tail_fused(const bf16_t* __restrict__ obufbf,
    const bf16_t* __restrict__ oWt, const float* __restrict__ ob,
    const float* __restrict__ ln1g, const float* __restrict__ ln1b,
    const bf16_t* __restrict__ W1t, const float* __restrict__ b1,
    const bf16_t* __restrict__ W2t, const float* __restrict__ b2,
    const float* __restrict__ ln2g, const float* __restrict__ ln2b,
    float* __restrict__ btok, bf16_t* __restrict__ btokbf,
    const bf16_t* __restrict__ nqWt, const float* __restrict__ nqb,
    const bf16_t* __restrict__ nkWt, const float* __restrict__ nkb,
    const bf16_t* __restrict__ nvWt, const float* __restrict__ nvb,
    bf16_t* __restrict__ nqo, bf16_t* __restrict__ nko, bf16_t* __restrict__ nvo) {
  __shared__ __align__(16) bf16_t Alds[16 * 16 * 8];   // 4KB
  __shared__ __align__(16) bf16_t Blds[128 * 16 * 8];  // 32KB streamed
  __shared__ __align__(16) bf16_t Hlds[16 * 512];      // 16KB hidden
  __shared__ float lnredS[16][8], lnredQ[16][8];       // 1KB cross-wave LN
  const int tid = threadIdx.x, m0 = blockIdx.x * 16;
  const int w = tid >> 6, lane = tid & 63, fcol = lane & 15, g = lane >> 4;
  const int cb = w * 16;                    // this wave's 16-col slice
  const int arow = fcol;                    // A row within the 16-row tile
  if (tid < 256) {
    int row = tid >> 4, kc = tid & 15;      // 16 rows * 16 kb
    uint4 d = *(const uint4*)(obufbf + (size_t)(m0 + row) * 128 + kc * 8);
    *(uint4*)&Alds[(row * 16 + (kc ^ (row & 7))) * 8] = d;
  }
#pragma unroll
  for (int it = 0; it < 4; ++it) {
    int u = tid + it * 512;                 // < 2048
    int col = u >> 4, kcb = u & 15;
    uint4 d = *(const uint4*)(oWt + (size_t)col * 128 + kcb * 8);
    *(uint4*)&Blds[(col * 16 + (kcb ^ (col & 7))) * 8] = d;
  }
  __syncthreads();
  // ---- oproj GEMM (per wave: 16 rows x 16 cols) ----
  f32x4 acc = {0.f, 0.f, 0.f, 0.f};
#pragma unroll
  for (int ks = 0; ks < 4; ++ks) {
    bf16x8 a = *(const bf16x8*)&Alds[(arow * 16 + ((ks * 4 + g) ^ (arow & 7))) * 8];
    const int bcol = cb + fcol;
    bf16x8 b = *(const bf16x8*)&Blds[(bcol * 16 + ((ks * 4 + g) ^ (bcol & 7))) * 8];
    acc = __builtin_amdgcn_mfma_f32_16x16x32_bf16(a, b, acc, 0, 0, 0);
  }
  // ---- +ob +residual, LN1 (cross-wave 8-slice combine) ----
  float lnr[4];
  {
    float s_[4], q_[4];
    const int col = cb + fcol;
    const float bv = ob[col];
#pragma unroll
    for (int r = 0; r < 4; ++r) {
      const int row = m0 + 4 * g + r;
      float val = acc[r] + bv + btok[(size_t)row * 128 + col];
      lnr[r] = val;
      s_[r] = val; q_[r] = val * val;
    }
#pragma unroll
    for (int m = 1; m <= 8; m <<= 1)
#pragma unroll
      for (int r = 0; r < 4; ++r) {
        s_[r] += __shfl_xor(s_[r], m); q_[r] += __shfl_xor(q_[r], m);
      }
    if (fcol == 0) {
#pragma unroll
      for (int r = 0; r < 4; ++r) {
        lnredS[4 * g + r][w] = s_[r];
        lnredQ[4 * g + r][w] = q_[r];
      }
    }
    __syncthreads();
    float mean[4], rs[4];
#pragma unroll
    for (int r = 0; r < 4; ++r) {
      const int rl = 4 * g + r;
      float S = 0.f, Q = 0.f;
#pragma unroll
      for (int ww = 0; ww < 8; ++ww) { S += lnredS[rl][ww]; Q += lnredQ[rl][ww]; }
      mean[r] = S * (1.f / 128.f);
      rs[r] = rsqrtf(Q * (1.f / 128.f) - mean[r] * mean[r] + 1e-5f);
    }
    const float gv = ln1g[col], bv2 = ln1b[col];
#pragma unroll
    for (int r = 0; r < 4; ++r) {
      float v2 = (lnr[r] - mean[r]) * rs[r] * gv + bv2;
      lnr[r] = v2;
      const int rowL = 4 * g + r;
      Alds[(rowL * 16 + ((col >> 3) ^ (rowL & 7))) * 8 + (col & 7)] = (bf16_t)v2;
    }
  }
  __syncthreads();
  // ---- FFN phase 1: Hlds = gelu(ln1 @ W1 + b1) ----
  for (int nc = 0; nc < 4; ++nc) {
#pragma unroll
    for (int it = 0; it < 4; ++it) {
      int u = tid + it * 512;
      int col = u >> 4, kcb = u & 15;
      uint4 d = *(const uint4*)(W1t + (size_t)(nc * 128 + col) * 128 + kcb * 8);
      *(uint4*)&Blds[(col * 16 + (kcb ^ (col & 7))) * 8] = d;
    }
    __syncthreads();
    f32x4 a1 = {0.f, 0.f, 0.f, 0.f};
#pragma unroll
    for (int ks = 0; ks < 4; ++ks) {
      bf16x8 a = *(const bf16x8*)&Alds[(arow * 16 + ((ks * 4 + g) ^ (arow & 7))) * 8];
      const int bcol = cb + fcol;
      bf16x8 b = *(const bf16x8*)&Blds[(bcol * 16 + ((ks * 4 + g) ^ (bcol & 7))) * 8];
      a1 = __builtin_amdgcn_mfma_f32_16x16x32_bf16(a, b, a1, 0, 0, 0);
    }
    {
      const int c = nc * 128 + cb + fcol;
      const float bv = b1[c];
      const int kb = c >> 3, within = c & 7;
#pragma unroll
      for (int r = 0; r < 4; ++r) {
        const int row = 4 * g + r;
        const int kbs = kb ^ (row & 7);
        Hlds[row * 512 + kbs * 8 + within] = (bf16_t)egelu(a1[r] + bv);
      }
    }
    __syncthreads();
  }
  // ---- FFN phase 2: acc2 = H @ W2 ----
  f32x4 acc2 = {0.f, 0.f, 0.f, 0.f};
  for (int kc = 0; kc < 4; ++kc) {
#pragma unroll
    for (int it = 0; it < 4; ++it) {
      int u = tid + it * 512;
      int col = u >> 4, kcb = u & 15;
      uint4 d = *(const uint4*)(W2t + (size_t)col * 512 + kc * 128 + kcb * 8);
      *(uint4*)&Blds[(col * 16 + (kcb ^ (col & 7))) * 8] = d;
    }
    __syncthreads();
#pragma unroll
    for (int ks = 0; ks < 4; ++ks) {
      const int kb = kc * 16 + ks * 4 + g;
      const int kbs = kb ^ (arow & 7);
      bf16x8 a = *(const bf16x8*)&Hlds[arow * 512 + kbs * 8];
      const int bcol = cb + fcol;
      bf16x8 b = *(const bf16x8*)&Blds[(bcol * 16 + ((ks * 4 + g) ^ (bcol & 7))) * 8];
      acc2 = __builtin_amdgcn_mfma_f32_16x16x32_bf16(a, b, acc2, 0, 0, 0);
    }
    __syncthreads();
  }
  // ---- +b2 +ln1-residual, LN2 -> btok/btokbf (+ Alds for next qkv) ----
  {
    float s_[4], q_[4];
    const int col = cb + fcol;
    const float bv = b2[col];
#pragma unroll
    for (int r = 0; r < 4; ++r) {
      float val = acc2[r] + bv + lnr[r];
      lnr[r] = val;
      s_[r] = val; q_[r] = val * val;
    }
#pragma unroll
    for (int m = 1; m <= 8; m <<= 1)
#pragma unroll
      for (int r = 0; r < 4; ++r) {
        s_[r] += __shfl_xor(s_[r], m); q_[r] += __shfl_xor(q_[r], m);
      }
    if (fcol == 0) {
#pragma unroll
      for (int r = 0; r < 4; ++r) {
        lnredS[4 * g + r][w] = s_[r];
        lnredQ[4 * g + r][w] = q_[r];
      }
    }
    __syncthreads();
    float mean[4], rs[4];
#pragma unroll
    for (int r = 0; r < 4; ++r) {
      const int rl = 4 * g + r;
      float S = 0.f, Q = 0.f;
#pragma unroll
      for (int ww = 0; ww < 8; ++ww) { S += lnredS[rl][ww]; Q += lnredQ[rl][ww]; }
      mean[r] = S * (1.f / 128.f);
      rs[r] = rsqrtf(Q * (1.f / 128.f) - mean[r] * mean[r] + 1e-5f);
    }
    const float gv = ln2g[col], bv2 = ln2b[col];
#pragma unroll
    for (int r = 0; r < 4; ++r) {
      const int row = m0 + 4 * g + r;
      float oval = (lnr[r] - mean[r]) * rs[r] * gv + bv2;
      btok[(size_t)row * 128 + col] = oval;
      btokbf[(size_t)row * 128 + col] = (bf16_t)oval;
      if (nqWt) {
        const int rowL = 4 * g + r;
        Alds[(rowL * 16 + ((col >> 3) ^ (rowL & 7))) * 8 + (col & 7)] = (bf16_t)oval;
      }
    }
  }
  // ---- next-layer qkv from LN2 output (Alds) ----
  if (nqWt) {
    __syncthreads();
    const bf16_t* Ws[3] = {nqWt, nkWt, nvWt};
    const float* bs[3] = {nqb, nkb, nvb};
    bf16_t* Cs[3] = {nqo, nko, nvo};
    for (int zz = 0; zz < 3; ++zz) {
      const bf16_t* Wt = Ws[zz];
#pragma unroll
      for (int it = 0; it < 4; ++it) {
        int u = tid + it * 512;
        int col = u >> 4, kcb = u & 15;
        uint4 d = *(const uint4*)(Wt + (size_t)col * 128 + kcb * 8);
        *(uint4*)&Blds[(col * 16 + (kcb ^ (col & 7))) * 8] = d;
      }
      __syncthreads();
      f32x4 aq = {0.f, 0.f, 0.f, 0.f};
#pragma unroll
      for (int ks = 0; ks < 4; ++ks) {
        bf16x8 a = *(const bf16x8*)&Alds[(arow * 16 + ((ks * 4 + g) ^ (arow & 7))) * 8];
        const int bcol = cb + fcol;
        bf16x8 b = *(const bf16x8*)&Blds[(bcol * 16 + ((ks * 4 + g) ^ (bcol & 7))) * 8];
        aq = __builtin_amdgcn_mfma_f32_16x16x32_bf16(a, b, aq, 0, 0, 0);
      }
      const float bv = bs[zz][cb + fcol];
      bf16_t* C = Cs[zz];
#pragma unroll
      for (int r = 0; r < 4; ++r) {
        const int row = m0 + 4 * g + r;
        C[(size_t)row * 128 + cb + fcol] = (bf16_t)(aq[r] + bv);
      }
      __syncthreads();
    }
  }
}

// ---------------- fused readout v2: 1024 threads ---------------------------
__global__ __launch_bounds__(1024) void readout_fused(const float* __restrict__ B,
    const bf16_t* __restrict__ Bbf, const float* __restrict__ slots,
    const float* __restrict__ task_q, const float* __restrict__ memg,
    const float* __restrict__ membt, const float* __restrict__ headW,
    const float* __restrict__ headb, float* __restrict__ out) {
  __shared__ __align__(16) bf16_t Ssh[64 * 16 * 8];   // 16KB
  __shared__ __align__(16) bf16_t Bsh[208 * 128];     // 53KB
  __shared__ float wcsh[4][208];
  __shared__ __align__(16) float tq[128];
  __shared__ float ras[KK];
  __shared__ float wc[208];
  __shared__ float red1[4], red2[4];
  __shared__ float hv2[1024], mv2[1024];              // 8KB
  __shared__ float hv[128], mv[128], rv[128];
  __shared__ float stats[2];
  const int b = blockIdx.x, tid = threadIdx.x;
  const int w = tid >> 6, lane = tid & 63, fcol = lane & 15, g = lane >> 4;
  {
    int u = tid;                            // 1024 = 64 rows * 16 kb
    int row = u >> 4, kb = u & 15;
    const float* sp = slots + (size_t)row * 128 + kb * 8;
    bf16_t tmp[8];
#pragma unroll
    for (int e = 0; e < 8; ++e) tmp[e] = (bf16_t)sp[e];
    *(uint4*)&Ssh[(row * 16 + (kb ^ (row & 7))) * 8] = *(uint4*)tmp;
  }
#pragma unroll
  for (int it = 0; it < 4; ++it) {
    int u = tid + it * 1024;                // < 3328
    if (u < 3328) {
      int c = u >> 4, kb = u & 15;
      uint4 d = {0u, 0u, 0u, 0u};
      if (c < KK) d = *(const uint4*)(Bbf + (size_t)(b * KK + c) * 128 + kb * 8);
      *(uint4*)&Bsh[(c * 16 + (kb ^ (c & 7))) * 8] = d;
    }
  }
  if (tid < 128) tq[tid] = task_q[tid];
  __syncthreads();
  // ---- slot scores via MFMA (waves 0..3) ----
  if (w < 4) {
    bf16x8 afr[4];
#pragma unroll
    for (int ks = 0; ks < 4; ++ks) {
      const int arow = 16 * w + fcol;
      afr[ks] = *(const bf16x8*)&Ssh[(arow * 16 + ((ks * 4 + g) ^ (arow & 7))) * 8];
    }
    f32x4 acc[13];
#pragma unroll
    for (int ct = 0; ct < 13; ++ct) {
      acc[ct] = (f32x4){0.f, 0.f, 0.f, 0.f};
#pragma unroll
      for (int ks = 0; ks < 4; ++ks) {
        const int bcol = ct * 16 + fcol;
        bf16x8 bb = *(const bf16x8*)&Bsh[(bcol * 16 + ((ks * 4 + g) ^ (bcol & 7))) * 8];
        acc[ct] = __builtin_amdgcn_mfma_f32_16x16x32_bf16(afr[ks], bb, acc[ct], 0, 0, 0);
      }
    }
    if (fcol >= 8) { acc[12][0] = -1e30f; acc[12][1] = -1e30f; acc[12][2] = -1e30f; acc[12][3] = -1e30f; }
    const float s2 = 0.08838834764831845f * 1.4426950408889634f;
    float wcp[13];
#pragma unroll
    for (int ct = 0; ct < 13; ++ct) wcp[ct] = 0.f;
#pragma unroll
    for (int r = 0; r < 4; ++r) {
      float m = acc[0][r];
#pragma unroll
      for (int ct = 1; ct < 13; ++ct) m = fmaxf(m, acc[ct][r]);
      m = fmaxf(m, __shfl_xor(m, 1));
      m = fmaxf(m, __shfl_xor(m, 2));
      m = fmaxf(m, __shfl_xor(m, 4));
      m = fmaxf(m, __shfl_xor(m, 8));
      float l = 0.f;
      float p[13];
#pragma unroll
      for (int ct = 0; ct < 13; ++ct) {
        p[ct] = fastexp2((acc[ct][r] - m) * s2);
        l += p[ct];
      }
      l += __shfl_xor(l, 1);
      l += __shfl_xor(l, 2);
      l += __shfl_xor(l, 4);
      l += __shfl_xor(l, 8);
      const float inv = fastrcp(l);
#pragma unroll
      for (int ct = 0; ct < 13; ++ct) wcp[ct] = fmaf(p[ct], inv, wcp[ct]);
    }
#pragma unroll
    for (int ct = 0; ct < 13; ++ct) {
      wcp[ct] += __shfl_xor(wcp[ct], 16);
      wcp[ct] += __shfl_xor(wcp[ct], 32);
      if (g == 0) wcsh[w][ct * 16 + fcol] = wcp[ct];
    }
  }
  // ---- ra = softmax(b . task_q / sqrt(128)) on threads 0..255 ----
  if (tid < 256) {
    float sc = -1e30f;
    if (tid < KK) {
      const float* br = B + (size_t)(b * KK + tid) * DDIM;
      float a = 0.f;
#pragma unroll
      for (int d4 = 0; d4 < 32; d4++) {
        float4 bb = *(const float4*)(br + d4 * 4);
        float4 ss = *(const float4*)(tq + d4 * 4);
        a += bb.x * ss.x + bb.y * ss.y + bb.z * ss.z + bb.w * ss.w;
      }
      sc = a * 0.08838834764831845f;
    }
    float mx = sc;
#pragma unroll
    for (int m = 1; m <= 32; m <<= 1) mx = fmaxf(mx, __shfl_xor(mx, m));
    if (lane == 0) red1[w] = mx;
    hv2[tid] = sc;                          // stash score in scratch
  }
  __syncthreads();
  if (tid < 256) {
    float sc = hv2[tid];
    float mx = fmaxf(fmaxf(red1[0], red1[1]), fmaxf(red1[2], red1[3]));
    float p = (tid < KK) ? __expf(sc - mx) : 0.f;
    float sm = p;
#pragma unroll
    for (int m = 1; m <= 32; m <<= 1) sm += __shfl_xor(sm, m);
    if (lane == 0) red2[w] = sm;
    hv2[tid] = p;                           // stash numerator
  }
  __syncthreads();
  if (tid < KK) {
    float sm = red2[0] + red2[1] + red2[2] + red2[3];
    ras[tid] = hv2[tid] / sm;
  }
  if (tid < 208)
    wc[tid] = (wcsh[0][tid] + wcsh[1][tid] + wcsh[2][tid] + wcsh[3][tid]) * (1.f / 64.f);
  __syncthreads();
  // ---- hv = ras @ B ; mv = wc @ B (8-way c-split) ----
  {
    const int d = tid & 127, oct = tid >> 7;   // 0..7
    float hd = 0.f, md = 0.f;
    const float* Bb = B + ((size_t)b * KK + oct * 25) * DDIM + d;
    const float* rp = ras + oct * 25;
    const float* wp = wc + oct * 25;
#pragma unroll 5
    for (int c = 0; c < 25; ++c) {
      float bv = Bb[(size_t)c * DDIM];
      hd = fmaf(rp[c], bv, hd);
      md = fmaf(wp[c], bv, md);
    }
    hv2[tid] = hd; mv2[tid] = md;
  }
  __syncthreads();
  if (tid < 128) {
    float hsum = 0.f, msum = 0.f;
#pragma unroll
    for (int o2 = 0; o2 < 8; ++o2) {
      hsum += hv2[tid + 128 * o2];
      msum += mv2[tid + 128 * o2];
    }
    hv[tid] = hsum; mv[tid] = msum;
  }
  __syncthreads();
  if (tid < 64) {
    float x0 = mv[tid], x1 = mv[tid + 64];
    float s = x0 + x1, qq = x0 * x0 + x1 * x1;
#pragma unroll
    for (int m = 1; m <= 32; m <<= 1) { s += __shfl_xor(s, m); qq += __shfl_xor(qq, m); }
    if (tid == 0) { stats[0] = s; stats[1] = qq; }
  }
  __syncthreads();
  float mean = stats[0] * (1.f / 128.f);
  float var = stats[1] * (1.f / 128.f) - mean * mean;
  float rs = rsqrtf(var + 1e-5f);
  if (tid < 128) rv[tid] = hv[tid] + (mv[tid] - mean) * rs * memg[tid] + membt[tid];
  __syncthreads();
  if (tid < OUTN) {
    float a = headb[tid];
    for (int dd = 0; dd < 128; dd++) a = fmaf(rv[dd], headW[dd * OUTN + tid], a);
    out[b * OUTN + tid] = a;
  }
}

// ---------------------------------------------------------------------------
extern "C" void kernel_launch(void* const* d_in, const int* in_sizes, int n_in,
                              void* d_out, int out_size, void* d_ws, size_t ws_size,
                              hipStream_t stream) {
  (void)in_sizes; (void)n_in; (void)out_size; (void)ws_size;
  const float* x        = (const float*)d_in[0];
  const float* role_emb = (const float*)d_in[1];
  const float* filler_w = (const float*)d_in[2];
  const float* qW = (const float*)d_in[3];
  const float* qb = (const float*)d_in[4];
  const float* kW = (const float*)d_in[5];
  const float* kb = (const float*)d_in[6];
  const float* vW = (const float*)d_in[7];
  const float* vb = (const float*)d_in[8];
  const float* oW = (const float*)d_in[9];
  const float* ob = (const float*)d_in[10];
  const float* relW1 = (const float*)d_in[11];
  const float* relb1 = (const float*)d_in[12];
  const float* relW2 = (const float*)d_in[13];
  const float* relb2 = (const float*)d_in[14];
  const float* ln1g = (const float*)d_in[15];
  const float* ln1b = (const float*)d_in[16];
  const float* ln2g = (const float*)d_in[17];
  const float* ln2b = (const float*)d_in[18];
  const float* fW1 = (const float*)d_in[19];
  const float* fb1 = (const float*)d_in[20];
  const float* fW2 = (const float*)d_in[21];
  const float* fb2 = (const float*)d_in[22];
  const float* slots = (const float*)d_in[23];
  const float* memg = (const float*)d_in[24];
  const float* memb = (const float*)d_in[25];
  const float* taskq = (const float*)d_in[26];
  const float* headW = (const float*)d_in[27];
  const float* headb = (const float*)d_in[28];
  float* out = (float*)d_out;
  (void)relb2;  // dropped: softmax shift-invariance

  // workspace layout (float-slot offsets; all 16B aligned)
  float* fws  = (float*)d_ws;
  float*  btok   = fws;                       // 204800 f
  bf16_t* btokbf = (bf16_t*)(fws + 204800);   // 204800 bf16
  bf16_t* qbf    = (bf16_t*)(fws + 307200);   // 204800 bf16
  bf16_t* kbf    = (bf16_t*)(fws + 409600);   // 204800 bf16
  bf16_t* vbf    = (bf16_t*)(fws + 512000);   // 204800 bf16
  bf16_t* obufbf = (bf16_t*)(fws + 614400);   // 204800 bf16
  bf16_t* wtb    = (bf16_t*)(fws + 716800);   // 589824 bf16 (end ~4.0MB)
  bf16_t* qWt = wtb, *kWt = wtb + 49152, *vWt = wtb + 98304, *oWt = wtb + 147456;
  bf16_t* fW1t = wtb + 196608, *fW2t = wtb + 393216;

  prep_kernel<<<152, 256, 0, stream>>>(qW, kW, vW, oW, fW1, fW2, wtb,
      x, role_emb, filler_w, btok, btokbf);
  qkv_mfma<<<dim3(50, 3), 256, 0, stream>>>(btokbf,
      qWt, qb, kWt, kb, vWt, vb, qbf, kbf, vbf);
  for (int l = 0; l < LLAY; l++) {
    rel_attn_mfma<<<dim3(25, 32), 512, 0, stream>>>(qbf, kbf, vbf,
        relW1 + l * 3072, relb1 + l * 32, relW2 + l * 32, obufbf);
    const bool nx = (l + 1 < LLAY);
    tail_fused<<<100, 512, 0, stream>>>(obufbf, oWt + l * 16384, ob + l * 128,
        ln1g + l * 128, ln1b + l * 128, fW1t + l * 65536, fb1 + l * 512,
        fW2t + l * 65536, fb2 + l * 128, ln2g + l * 128, ln2b + l * 128,
        btok, btokbf,
        nx ? qWt + (l + 1) * 16384 : (const bf16_t*)nullptr,
        nx ? qb + (l + 1) * 128 : (const float*)nullptr,
        nx ? kWt + (l + 1) * 16384 : (const bf16_t*)nullptr,
        nx ? kb + (l + 1) * 128 : (const float*)nullptr,
        nx ? vWt + (l + 1) * 16384 : (const bf16_t*)nullptr,
        nx ? vb + (l + 1) * 128 : (const float*)nullptr,
        qbf, kbf, vbf);
  }
  readout_fused<<<8, 1024, 0, stream>>>(btok, btokbf, slots, taskq,
      memg, memb, headW, headb, out);
}

// Round 15
// 195.204 us; speedup vs baseline: 1.5015x; 1.0716x over previous
//
#include <hip/hip_runtime.h>
#include <math.h>

#define BQ 8
#define CC 2048
#define DDIM 128
#define LLAY 3
#define HH 4
#define KK 200
#define SSLOT 64
#define OUTN 24
#define DH 32

typedef __bf16 bf16_t;
typedef __bf16 bf16x8 __attribute__((ext_vector_type(8)));
typedef float f32x4 __attribute__((ext_vector_type(4)));

__device__ __forceinline__ float fastrcp(float x) {
#if __has_builtin(__builtin_amdgcn_rcpf)
  return __builtin_amdgcn_rcpf(x);
#else
  return 1.0f / x;
#endif
}
__device__ __forceinline__ float fastexp2(float x) {
#if __has_builtin(__builtin_amdgcn_exp2f)
  return __builtin_amdgcn_exp2f(x);
#else
  return exp2f(x);
#endif
}
// gelu tanh-approx: x - x/(1+e^y); inf/underflow give exact limits
__device__ __forceinline__ float fgelu2(float x) {
  float s = x * x;
  float inner = fmaf(0.044715f * s, x, x);
  float e = fastexp2(inner * 2.302118610509359f);  // 2*0.79788456*log2(e)
  float r = fastrcp(1.f + e);
  return fmaf(-x, r, x);
}
__device__ __forceinline__ float egelu(float x) {
  return 0.5f * x * (1.f + erff(x * 0.7071067811865476f));
}

// ---------------- prep: wconv (blocks 0..143) + topk+bind (144..151) -------
__global__ __launch_bounds__(256) void prep_kernel(
    const float* __restrict__ qW, const float* __restrict__ kW,
    const float* __restrict__ vW, const float* __restrict__ oW,
    const float* __restrict__ fW1, const float* __restrict__ fW2,
    bf16_t* __restrict__ wtb,
    const float* __restrict__ x, const float* __restrict__ role_emb,
    const float* __restrict__ fw, float* __restrict__ btok,
    bf16_t* __restrict__ btokbf) {
  __shared__ float Ts[64][65];
  __shared__ float svals[KK];
  __shared__ int sidx[KK];
  __shared__ int red[4];
  __shared__ int cnt;
  const int blk = blockIdx.x, tid = threadIdx.x;
  if (blk < 144) {
    const int t = blk;
    const float* src; bf16_t* dst; int N, K, k0, n0;
    if (t < 48) {
      int which = t / 12, rem = t % 12;
      int l = rem >> 2, tt = rem & 3;
      N = 128; K = 128; k0 = (tt >> 1) * 64; n0 = (tt & 1) * 64;
      src = (which == 0 ? qW : which == 1 ? kW : which == 2 ? vW : oW) + l * 16384;
      dst = wtb + which * 49152 + l * 16384;
    } else if (t < 96) {
      int t2 = t - 48, l = t2 >> 4, tt = t2 & 15;
      N = 512; K = 128; k0 = (tt >> 3) * 64; n0 = (tt & 7) * 64;
      src = fW1 + l * 65536;
      dst = wtb + 196608 + l * 65536;
    } else {
      int t3 = t - 96, l = t3 >> 4, tt = t3 & 15;
      N = 128; K = 512; k0 = (tt >> 1) * 64; n0 = (tt & 1) * 64;
      src = fW2 + l * 65536;
      dst = wtb + 393216 + l * 65536;
    }
#pragma unroll
    for (int i = 0; i < 16; ++i) {
      int u = tid + i * 256;
      int r = u >> 6, c = u & 63;
      Ts[r][c] = src[(size_t)(k0 + r) * N + n0 + c];
    }
    __syncthreads();
#pragma unroll
    for (int i = 0; i < 16; ++i) {
      int u = tid + i * 256;
      int rn = u >> 6, ck = u & 63;
      dst[(size_t)(n0 + rn) * K + k0 + ck] = (bf16_t)Ts[ck][rn];
    }
    return;
  }
  // ---- top-k + bind for batch b ----
  const int b = blk - 144;
  float xv[8]; unsigned xb[8];
#pragma unroll
  for (int t = 0; t < 8; t++) {
    float v = x[b * CC + t * 256 + tid];
    xv[t] = v;
    xb[t] = __float_as_uint(v);
  }
  unsigned lo = 0u, hi = 0x7f800000u;
  while (lo < hi) {
    unsigned mid = (lo + hi) >> 1;
    int c = 0;
#pragma unroll
    for (int t = 0; t < 8; t++) c += (xb[t] > mid) ? 1 : 0;
#pragma unroll
    for (int m = 1; m <= 32; m <<= 1) c += __shfl_xor(c, m);
    if ((tid & 63) == 0) red[tid >> 6] = c;
    __syncthreads();
    int ct = red[0] + red[1] + red[2] + red[3];
    __syncthreads();
    if (ct >= KK) lo = mid + 1; else hi = mid;
  }
  const unsigned thr = lo;
  if (tid == 0) cnt = 0;
  __syncthreads();
#pragma unroll
  for (int t = 0; t < 8; t++) {
    if (xb[t] > thr) {
      int p = atomicAdd(&cnt, 1);
      svals[p] = log1pf(xv[t]);
      sidx[p] = t * 256 + tid;
    }
  }
  __syncthreads();
#pragma unroll
  for (int t = 0; t < 8; t++) {
    if (xb[t] == thr) {
      int p = atomicAdd(&cnt, 1);
      if (p < KK) {
        svals[p] = log1pf(xv[t]);
        sidx[p] = t * 256 + tid;
      }
    }
  }
  __syncthreads();
  for (int u = tid; u < KK * DDIM; u += 256) {
    int dd = u & 127, t = u >> 7;
    float v = svals[t];
    float fill = egelu(v * fw[dd]);
    float val = role_emb[(size_t)sidx[t] * DDIM + dd] * fill;
    btok[(size_t)b * KK * DDIM + u] = val;
    btokbf[(size_t)b * KK * DDIM + u] = (bf16_t)val;
  }
}

// ---------------- qkv (layer 0 only): BM=32, grid (50,3); outputs bf16 -----
__global__ __launch_bounds__(256) void qkv_mfma(const bf16_t* __restrict__ A,
    const bf16_t* __restrict__ qWt, const float* __restrict__ qb,
    const bf16_t* __restrict__ kWt, const float* __restrict__ kb,
    const bf16_t* __restrict__ vWt, const float* __restrict__ vb,
    bf16_t* __restrict__ qo, bf16_t* __restrict__ ko, bf16_t* __restrict__ vo) {
  __shared__ __align__(16) bf16_t Alds[32 * 16 * 8];
  __shared__ __align__(16) bf16_t Blds[128 * 16 * 8];
  const int tid = threadIdx.x, m0 = blockIdx.x * 32, z = blockIdx.y;
  const bf16_t* Wt; const float* bias; bf16_t* C;
  if (z == 0) { Wt = qWt; bias = qb; C = qo; }
  else if (z == 1) { Wt = kWt; bias = kb; C = ko; }
  else { Wt = vWt; bias = vb; C = vo; }
#pragma unroll
  for (int it = 0; it < 2; ++it) {
    int u = tid + it * 256;                 // < 512
    int row = u >> 4, kc = u & 15;
    uint4 d = *(const uint4*)(A + (size_t)(m0 + row) * 128 + kc * 8);
    *(uint4*)&Alds[(row * 16 + (kc ^ (row & 7))) * 8] = d;
  }
#pragma unroll
  for (int it = 0; it < 8; ++it) {
    int u = tid + it * 256;
    int col = u >> 4, kcb = u & 15;
    uint4 d = *(const uint4*)(Wt + (size_t)col * 128 + kcb * 8);
    *(uint4*)&Blds[(col * 16 + (kcb ^ (col & 7))) * 8] = d;
  }
  __syncthreads();
  const int w = tid >> 6, lane = tid & 63, fcol = lane & 15, g = lane >> 4;
  const int wr = w & 1, wn = w >> 1;
  f32x4 acc[4];
#pragma unroll
  for (int ni = 0; ni < 4; ++ni) acc[ni] = (f32x4){0.f, 0.f, 0.f, 0.f};
#pragma unroll
  for (int ks = 0; ks < 4; ++ks) {
    const int arow = 16 * wr + fcol;
    bf16x8 a = *(const bf16x8*)&Alds[(arow * 16 + ((ks * 4 + g) ^ (arow & 7))) * 8];
#pragma unroll
    for (int ni = 0; ni < 4; ++ni) {
      const int bcol = wn * 64 + ni * 16 + fcol;
      bf16x8 b = *(const bf16x8*)&Blds[(bcol * 16 + ((ks * 4 + g) ^ (bcol & 7))) * 8];
      acc[ni] = __builtin_amdgcn_mfma_f32_16x16x32_bf16(a, b, acc[ni], 0, 0, 0);
    }
  }
#pragma unroll
  for (int ni = 0; ni < 4; ++ni) {
    const int col = wn * 64 + ni * 16 + fcol;
    const float bv = bias[col];
#pragma unroll
    for (int r = 0; r < 4; ++r) {
      const int row = m0 + 16 * wr + 4 * g + r;
      C[(size_t)row * 128 + col] = (bf16_t)(acc[ni][r] + bv);
    }
  }
}

// ---------------- fused relational attention: (512,4) proven profile -------
__global__ __launch_bounds__(512, 4) void rel_attn_mfma(
    const bf16_t* __restrict__ qbf, const bf16_t* __restrict__ kbf,
    const bf16_t* __restrict__ vbf,
    const float* __restrict__ W1g, const float* __restrict__ b1g,
    const float* __restrict__ w2p, bf16_t* __restrict__ o) {
  __shared__ __align__(16) bf16_t ksh[208 * 32];   // 13312 B, 16B-block swizz
  __shared__ __align__(16) bf16_t vtsh[32 * 224];  // 14336 B, V^T [f'][j]
  __shared__ __align__(16) bf16_t psh[8 * 224];    // 3584 B, P [i][j]
  __shared__ __align__(16) bf16_t W1ki[32 * 66];   // 4224 B (k,i) pairs, +2 pad
  __shared__ __align__(16) bf16_t qsh[8 * 32];     // 512 B
  __shared__ __align__(16) bf16_t qtshb[8 * 32];   // 512 B    (sum 36480)
  const int tid = threadIdx.x;
  const int bh = blockIdx.y, bb = bh >> 2, h = bh & 3;
  const int i0 = blockIdx.x * 8;
  const bf16_t* kgb = kbf + (size_t)(bb * KK) * DDIM + h * DH;
  const bf16_t* vgb = vbf + (size_t)(bb * KK) * DDIM + h * DH;
  const bf16_t* qgb = qbf + (size_t)(bb * KK) * DDIM + h * DH;
  // ---- stage K (16B units, swizzled) ----
#pragma unroll
  for (int it = 0; it < 2; ++it) {
    int u = tid + it * 512;                 // < 832
    if (u < 832) {
      int j = u >> 2, bi = u & 3;
      uint4 d = {0u, 0u, 0u, 0u};
      if (j < KK) d = *(const uint4*)(kgb + (size_t)j * DDIM + bi * 8);
      *(uint4*)&ksh[j * 32 + (bi ^ ((j >> 1) & 3)) * 8] = d;
    }
  }
  // ---- stage V^T (stride 224, cols >=200 zero) ----
#pragma unroll
  for (int it = 0; it < 7; ++it) {
    int u = tid + it * 512;                 // < 3328 = 104 j-pairs * 32 f
    if (u < 3328) {
      int jp = u >> 5, f = u & 31;
      int j0 = jp * 2;
      bf16_t a0 = (j0 < KK) ? vgb[(size_t)j0 * DDIM + f] : (bf16_t)0.f;
      bf16_t a1 = (j0 + 1 < KK) ? vgb[(size_t)(j0 + 1) * DDIM + f] : (bf16_t)0.f;
      union { bf16_t h2[2]; unsigned uu; } pk;
      pk.h2[0] = a0; pk.h2[1] = a1;
      *(unsigned*)&vtsh[f * 224 + j0] = pk.uu;
    }
  }
  if (tid < 256) {                          // vtsh pad cols 208..223
    int f = tid >> 3, cp = tid & 7;
    *(unsigned*)&vtsh[f * 224 + 208 + cp * 2] = 0u;
  }
  if (tid < 64) {                           // psh pad cols 208..223
    int r = tid >> 3, cp = tid & 7;
    *(unsigned*)&psh[r * 224 + 208 + cp * 2] = 0u;
  }
  // ---- stage W1ki (bf16, stride 66) ----
#pragma unroll
  for (int it = 0; it < 4; ++it) {
    int u = tid + it * 512;                 // < 2048
    int sel = u & 1, f = (u >> 1) & 31, e = u >> 6;
    W1ki[e * 66 + f * 2 + sel] = (bf16_t)W1g[(32 + sel * 32 + e) * 32 + f];
  }
  // ---- stage q (bf16) ----
  if (tid < 128) {
    int il = tid >> 4, ep = tid & 15;
    *(unsigned*)&qsh[il * 32 + ep * 2] =
        *(const unsigned*)(qgb + (size_t)(i0 + il) * DDIM + ep * 2);
  }
  __syncthreads();
  // ---- qtv = q @ W1q + b1 (W1q from global; L2-hot) ----
  if (tid < 256) {
    int il = tid >> 5, f = tid & 31;
    float a = b1g[f];
#pragma unroll
    for (int e = 0; e < 32; ++e)
      a = fmaf((float)qsh[il * 32 + e], W1g[e * 32 + f], a);
    qtshb[il * 32 + f] = (bf16_t)a;
  }
  __syncthreads();
  const int w = tid >> 6, lane = tid & 63;
  const int fcol = lane & 15, g = lane >> 4;
  const float w2c = 0.17677669529663687f * 1.4426950408889634f;
  float4 w2a = *(const float4*)(w2p + 4 * g);
  float4 w2b = *(const float4*)(w2p + 16 + 4 * g);
  w2a.x *= w2c; w2a.y *= w2c; w2a.z *= w2c; w2a.w *= w2c;
  w2b.x *= w2c; w2b.y *= w2c; w2b.z *= w2c; w2b.w *= w2c;
  // ---- score phase: one query per wave (il = w) ----
  {
    const int il = w;
    bf16x8 qv8 = *(const bf16x8*)&qsh[il * 32 + g * 8];
    bf16x8 bw0, bw1;
#pragma unroll
    for (int e8 = 0; e8 < 8; ++e8) {
      int e = g * 8 + e8;
      float qe = (float)qv8[e8];
      union { unsigned u; bf16_t h[2]; } k0_, k1_;
      k0_.u = *(const unsigned*)&W1ki[e * 66 + fcol * 2];
      k1_.u = *(const unsigned*)&W1ki[e * 66 + (fcol + 16) * 2];
      bw0[e8] = (bf16_t)fmaf(qe, (float)k0_.h[1], (float)k0_.h[0]);
      bw1[e8] = (bf16_t)fmaf(qe, (float)k1_.h[1], (float)k1_.h[0]);
    }
    const bf16_t* qtp = &qtshb[il * 32];
    const f32x4 cin0 = {(float)qtp[4 * g + 0], (float)qtp[4 * g + 1],
                        (float)qtp[4 * g + 2], (float)qtp[4 * g + 3]};
    const f32x4 cin1 = {(float)qtp[16 + 4 * g + 0], (float)qtp[16 + 4 * g + 1],
                        (float)qtp[16 + 4 * g + 2], (float)qtp[16 + 4 * g + 3]};
    float s[13];
#pragma unroll
    for (int jt = 0; jt < 13; ++jt) {
      int j = jt * 16 + fcol;
      bf16x8 af = *(const bf16x8*)&ksh[j * 32 + (g ^ ((j >> 1) & 3)) * 8];
      f32x4 acc0 = __builtin_amdgcn_mfma_f32_16x16x32_bf16(bw0, af, cin0, 0, 0, 0);
      f32x4 acc1 = __builtin_amdgcn_mfma_f32_16x16x32_bf16(bw1, af, cin1, 0, 0, 0);
      float t0 = fgelu2(acc0[0]) * w2a.x;
      t0 = fmaf(fgelu2(acc0[1]), w2a.y, t0);
      float t1 = fgelu2(acc0[2]) * w2a.z;
      t1 = fmaf(fgelu2(acc0[3]), w2a.w, t1);
      float t2 = fgelu2(acc1[0]) * w2b.x;
      t2 = fmaf(fgelu2(acc1[1]), w2b.y, t2);
      float t3 = fgelu2(acc1[2]) * w2b.z;
      t3 = fmaf(fgelu2(acc1[3]), w2b.w, t3);
      float t = (t0 + t1) + (t2 + t3);
      t += __shfl_xor(t, 16);
      t += __shfl_xor(t, 32);
      s[jt] = t;
    }
    if (fcol >= 8) s[12] = -1e30f;          // mask j >= 200
    float m = s[0];
#pragma unroll
    for (int jt = 1; jt < 13; ++jt) m = fmaxf(m, s[jt]);
    m = fmaxf(m, __shfl_xor(m, 1));
    m = fmaxf(m, __shfl_xor(m, 2));
    m = fmaxf(m, __shfl_xor(m, 4));
    m = fmaxf(m, __shfl_xor(m, 8));
    float l = 0.f;
#pragma unroll
    for (int jt = 0; jt < 13; ++jt) {
      float p = fastexp2(s[jt] - m);
      s[jt] = p;
      l += p;
    }
    l += __shfl_xor(l, 1);
    l += __shfl_xor(l, 2);
    l += __shfl_xor(l, 4);
    l += __shfl_xor(l, 8);
    const float inv = fastrcp(l);
    if (g == 0) {
#pragma unroll
      for (int jt = 0; jt < 13; ++jt)
        psh[il * 224 + jt * 16 + fcol] = (bf16_t)(s[jt] * inv);
    }
  }
  __syncthreads();
  // ---- PV (waves 0,1) ----
  if (w < 2) {
    f32x4 acc = {0.f, 0.f, 0.f, 0.f};
#pragma unroll
    for (int ks = 0; ks < 7; ++ks) {
      bf16x8 ap;
      if (fcol < 8) ap = *(const bf16x8*)&psh[fcol * 224 + ks * 32 + g * 8];
      else { bf16x8 z = {}; ap = z; }
      bf16x8 bv = *(const bf16x8*)&vtsh[(w * 16 + fcol) * 224 + ks * 32 + g * 8];
      acc = __builtin_amdgcn_mfma_f32_16x16x32_bf16(ap, bv, acc, 0, 0, 0);
    }
    if (g < 2) {
#pragma unroll
      for (int r = 0; r < 4; ++r) {
        int i = i0 + g * 4 + r;
        o[(size_t)(bb * KK + i) * DDIM + h * DH + w * 16 + fcol] = (bf16_t)acc[r];
      }
    }
  }
}

// ------ fused tail: BM=16, grid 100, 512 thr (8 col-slices of 16) ----------
__global__ __launch_bounds__(512) void tail_fused(const bf16_t* __restrict__ obufbf,
    const bf16_t* __restrict__ oWt, const float* __restrict__ ob,
    const float* __restrict__ ln1g, const float* __restrict__ ln1b,
    const bf16_t* __restrict__ W1t, const float* __restrict__ b1,
    const bf16_t* __restrict__ W2t, const float* __restrict__ b2,
    const float* __restrict__ ln2g, const float* __restrict__ ln2b,
    float* __restrict__ btok, bf16_t* __restrict__ btokbf,
    const bf16_t* __restrict__ nqWt, const float* __restrict__ nqb,
    const bf16_t* __restrict__ nkWt, const float* __restrict__ nkb,
    const bf16_t* __restrict__ nvWt, const float* __restrict__ nvb,
    bf16_t* __restrict__ nqo, bf16_t* __restrict__ nko, bf16_t* __restrict__ nvo) {
  __shared__ __align__(16) bf16_t Alds[16 * 16 * 8];   // 4KB
  __shared__ __align__(16) bf16_t Blds[128 * 16 * 8];  // 32KB streamed
  __shared__ __align__(16) bf16_t Hlds[16 * 512];      // 16KB hidden
  __shared__ float lnredS[16][8], lnredQ[16][8];       // 1KB cross-wave LN
  const int tid = threadIdx.x, m0 = blockIdx.x * 16;
  const int w = tid >> 6, lane = tid & 63, fcol = lane & 15, g = lane >> 4;
  const int cb = w * 16;                    // this wave's 16-col slice
  const int arow = fcol;                    // A row within the 16-row tile
  if (tid < 256) {
    int row = tid >> 4, kc = tid & 15;      // 16 rows * 16 kb
    uint4 d = *(const uint4*)(obufbf + (size_t)(m0 + row) * 128 + kc * 8);
    *(uint4*)&Alds[(row * 16 + (kc ^ (row & 7))) * 8] = d;
  }
#pragma unroll
  for (int it = 0; it < 4; ++it) {
    int u = tid + it * 512;                 // < 2048
    int col = u >> 4, kcb = u & 15;
    uint4 d = *(const uint4*)(oWt + (size_t)col * 128 + kcb * 8);
    *(uint4*)&Blds[(col * 16 + (kcb ^ (col & 7))) * 8] = d;
  }
  __syncthreads();
  // ---- oproj GEMM (per wave: 16 rows x 16 cols) ----
  f32x4 acc = {0.f, 0.f, 0.f, 0.f};
#pragma unroll
  for (int ks = 0; ks < 4; ++ks) {
    bf16x8 a = *(const bf16x8*)&Alds[(arow * 16 + ((ks * 4 + g) ^ (arow & 7))) * 8];
    const int bcol = cb + fcol;
    bf16x8 b = *(const bf16x8*)&Blds[(bcol * 16 + ((ks * 4 + g) ^ (bcol & 7))) * 8];
    acc = __builtin_amdgcn_mfma_f32_16x16x32_bf16(a, b, acc, 0, 0, 0);
  }
  // ---- +ob +residual, LN1 (cross-wave 8-slice combine) ----
  float lnr[4];
  {
    float s_[4], q_[4];
    const int col = cb + fcol;
    const float bv = ob[col];
#pragma unroll
    for (int r = 0; r < 4; ++r) {
      const int row = m0 + 4 * g + r;
      float val = acc[r] + bv + btok[(size_t)row * 128 + col];
      lnr[r] = val;
      s_[r] = val; q_[r] = val * val;
    }
#pragma unroll
    for (int m = 1; m <= 8; m <<= 1)
#pragma unroll
      for (int r = 0; r < 4; ++r) {
        s_[r] += __shfl_xor(s_[r], m); q_[r] += __shfl_xor(q_[r], m);
      }
    if (fcol == 0) {
#pragma unroll
      for (int r = 0; r < 4; ++r) {
        lnredS[4 * g + r][w] = s_[r];
        lnredQ[4 * g + r][w] = q_[r];
      }
    }
    __syncthreads();
    float mean[4], rs[4];
#pragma unroll
    for (int r = 0; r < 4; ++r) {
      const int rl = 4 * g + r;
      float S = 0.f, Q = 0.f;
#pragma unroll
      for (int ww = 0; ww < 8; ++ww) { S += lnredS[rl][ww]; Q += lnredQ[rl][ww]; }
      mean[r] = S * (1.f / 128.f);
      rs[r] = rsqrtf(Q * (1.f / 128.f) - mean[r] * mean[r] + 1e-5f);
    }
    const float gv = ln1g[col], bv2 = ln1b[col];
#pragma unroll
    for (int r = 0; r < 4; ++r) {
      float v2 = (lnr[r] - mean[r]) * rs[r] * gv + bv2;
      lnr[r] = v2;
      const int rowL = 4 * g + r;
      Alds[(rowL * 16 + ((col >> 3) ^ (rowL & 7))) * 8 + (col & 7)] = (bf16_t)v2;
    }
  }
  __syncthreads();
  // ---- FFN phase 1: Hlds = gelu(ln1 @ W1 + b1) ----
  for (int nc = 0; nc < 4; ++nc) {
#pragma unroll
    for (int it = 0; it < 4; ++it) {
      int u = tid + it * 512;
      int col = u >> 4, kcb = u & 15;
      uint4 d = *(const uint4*)(W1t + (size_t)(nc * 128 + col) * 128 + kcb * 8);
      *(uint4*)&Blds[(col * 16 + (kcb ^ (col & 7))) * 8] = d;
    }
    __syncthreads();
    f32x4 a1 = {0.f, 0.f, 0.f, 0.f};
#pragma unroll
    for (int ks = 0; ks < 4; ++ks) {
      bf16x8 a = *(const bf16x8*)&Alds[(arow * 16 + ((ks * 4 + g) ^ (arow & 7))) * 8];
      const int bcol = cb + fcol;
      bf16x8 b = *(const bf16x8*)&Blds[(bcol * 16 + ((ks * 4 + g) ^ (bcol & 7))) * 8];
      a1 = __builtin_amdgcn_mfma_f32_16x16x32_bf16(a, b, a1, 0, 0, 0);
    }
    {
      const int c = nc * 128 + cb + fcol;
      const float bv = b1[c];
      const int kb = c >> 3, within = c & 7;
#pragma unroll
      for (int r = 0; r < 4; ++r) {
        const int row = 4 * g + r;
        const int kbs = kb ^ (row & 7);
        Hlds[row * 512 + kbs * 8 + within] = (bf16_t)egelu(a1[r] + bv);
      }
    }
    __syncthreads();
  }
  // ---- FFN phase 2: acc2 = H @ W2 ----
  f32x4 acc2 = {0.f, 0.f, 0.f, 0.f};
  for (int kc = 0; kc < 4; ++kc) {
#pragma unroll
    for (int it = 0; it < 4; ++it) {
      int u = tid + it * 512;
      int col = u >> 4, kcb = u & 15;
      uint4 d = *(const uint4*)(W2t + (size_t)col * 512 + kc * 128 + kcb * 8);
      *(uint4*)&Blds[(col * 16 + (kcb ^ (col & 7))) * 8] = d;
    }
    __syncthreads();
#pragma unroll
    for (int ks = 0; ks < 4; ++ks) {
      const int kb = kc * 16 + ks * 4 + g;
      const int kbs = kb ^ (arow & 7);
      bf16x8 a = *(const bf16x8*)&Hlds[arow * 512 + kbs * 8];
      const int bcol = cb + fcol;
      bf16x8 b = *(const bf16x8*)&Blds[(bcol * 16 + ((ks * 4 + g) ^ (bcol & 7))) * 8];
      acc2 = __builtin_amdgcn_mfma_f32_16x16x32_bf16(a, b, acc2, 0, 0, 0);
    }
    __syncthreads();
  }
  // ---- +b2 +ln1-residual, LN2 -> btok/btokbf (+ Alds for next qkv) ----
  {
    float s_[4], q_[4];
    const int col = cb + fcol;
    const float bv = b2[col];
#pragma unroll
    for (int r = 0; r < 4; ++r) {
      float val = acc2[r] + bv + lnr[r];
      lnr[r] = val;
      s_[r] = val; q_[r] = val * val;
    }
#pragma unroll
    for (int m = 1; m <= 8; m <<= 1)
#pragma unroll
      for (int r = 0; r < 4; ++r) {
        s_[r] += __shfl_xor(s_[r], m); q_[r] += __shfl_xor(q_[r], m);
      }
    if (fcol == 0) {
#pragma unroll
      for (int r = 0; r < 4; ++r) {
        lnredS[4 * g + r][w] = s_[r];
        lnredQ[4 * g + r][w] = q_[r];
      }
    }
    __syncthreads();
    float mean[4], rs[4];
#pragma unroll
    for (int r = 0; r < 4; ++r) {
      const int rl = 4 * g + r;
      float S = 0.f, Q = 0.f;
#pragma unroll
      for (int ww = 0; ww < 8; ++ww) { S += lnredS[rl][ww]; Q += lnredQ[rl][ww]; }
      mean[r] = S * (1.f / 128.f);
      rs[r] = rsqrtf(Q * (1.f / 128.f) - mean[r] * mean[r] + 1e-5f);
    }
    const float gv = ln2g[col], bv2 = ln2b[col];
#pragma unroll
    for (int r = 0; r < 4; ++r) {
      const int row = m0 + 4 * g + r;
      float oval = (lnr[r] - mean[r]) * rs[r] * gv + bv2;
      btok[(size_t)row * 128 + col] = oval;
      btokbf[(size_t)row * 128 + col] = (bf16_t)oval;
      if (nqWt) {
        const int rowL = 4 * g + r;
        Alds[(rowL * 16 + ((col >> 3) ^ (rowL & 7))) * 8 + (col & 7)] = (bf16_t)oval;
      }
    }
  }
  // ---- next-layer qkv from LN2 output (Alds) ----
  if (nqWt) {
    __syncthreads();
    const bf16_t* Ws[3] = {nqWt, nkWt, nvWt};
    const float* bs[3] = {nqb, nkb, nvb};
    bf16_t* Cs[3] = {nqo, nko, nvo};
    for (int zz = 0; zz < 3; ++zz) {
      const bf16_t* Wt = Ws[zz];
#pragma unroll
      for (int it = 0; it < 4; ++it) {
        int u = tid + it * 512;
        int col = u >> 4, kcb = u & 15;
        uint4 d = *(const uint4*)(Wt + (size_t)col * 128 + kcb * 8);
        *(uint4*)&Blds[(col * 16 + (kcb ^ (col & 7))) * 8] = d;
      }
      __syncthreads();
      f32x4 aq = {0.f, 0.f, 0.f, 0.f};
#pragma unroll
      for (int ks = 0; ks < 4; ++ks) {
        bf16x8 a = *(const bf16x8*)&Alds[(arow * 16 + ((ks * 4 + g) ^ (arow & 7))) * 8];
        const int bcol = cb + fcol;
        bf16x8 b = *(const bf16x8*)&Blds[(bcol * 16 + ((ks * 4 + g) ^ (bcol & 7))) * 8];
        aq = __builtin_amdgcn_mfma_f32_16x16x32_bf16(a, b, aq, 0, 0, 0);
      }
      const float bv = bs[zz][cb + fcol];
      bf16_t* C = Cs[zz];
#pragma unroll
      for (int r = 0; r < 4; ++r) {
        const int row = m0 + 4 * g + r;
        C[(size_t)row * 128 + cb + fcol] = (bf16_t)(aq[r] + bv);
      }
      __syncthreads();
    }
  }
}

// ---------------- fused readout: slot-attention + task readout + head ------
__global__ __launch_bounds__(256) void readout_fused(const float* __restrict__ B,
    const bf16_t* __restrict__ Bbf, const float* __restrict__ slots,
    const float* __restrict__ task_q, const float* __restrict__ memg,
    const float* __restrict__ membt, const float* __restrict__ headW,
    const float* __restrict__ headb, float* __restrict__ out) {
  __shared__ __align__(16) bf16_t Ssh[64 * 16 * 8];
  __shared__ __align__(16) bf16_t Bsh[208 * 128];
  __shared__ float wcsh[4][208];
  __shared__ __align__(16) float tq[128];
  __shared__ float ras[KK];
  __shared__ float wc[208];
  __shared__ float red1[4], red2[4];
  __shared__ float hv2[256], mv2[256];
  __shared__ float hv[128], mv[128], rv[128];
  __shared__ float stats[2];
  const int b = blockIdx.x, tid = threadIdx.x;
  const int w = tid >> 6, lane = tid & 63, fcol = lane & 15, g = lane >> 4;
#pragma unroll
  for (int it = 0; it < 4; ++it) {
    int u = tid + it * 256;
    int row = u >> 4, kb = u & 15;
    const float* sp = slots + (size_t)row * 128 + kb * 8;
    bf16_t tmp[8];
#pragma unroll
    for (int e = 0; e < 8; ++e) tmp[e] = (bf16_t)sp[e];
    *(uint4*)&Ssh[(row * 16 + (kb ^ (row & 7))) * 8] = *(uint4*)tmp;
  }
#pragma unroll
  for (int it = 0; it < 13; ++it) {
    int u = tid + it * 256;
    int c = u >> 4, kb = u & 15;
    uint4 d = {0u, 0u, 0u, 0u};
    if (c < KK) d = *(const uint4*)(Bbf + (size_t)(b * KK + c) * 128 + kb * 8);
    *(uint4*)&Bsh[(c * 16 + (kb ^ (c & 7))) * 8] = d;
  }
  if (tid < 128) tq[tid] = task_q[tid];
  __syncthreads();
  {
    bf16x8 afr[4];
#pragma unroll
    for (int ks = 0; ks < 4; ++ks) {
      const int arow = 16 * w + fcol;
      afr[ks] = *(const bf16x8*)&Ssh[(arow * 16 + ((ks * 4 + g) ^ (arow & 7))) * 8];
    }
    f32x4 acc[13];
#pragma unroll
    for (int ct = 0; ct < 13; ++ct) {
      acc[ct] = (f32x4){0.f, 0.f, 0.f, 0.f};
#pragma unroll
      for (int ks = 0; ks < 4; ++ks) {
        const int bcol = ct * 16 + fcol;
        bf16x8 bb = *(const bf16x8*)&Bsh[(bcol * 16 + ((ks * 4 + g) ^ (bcol & 7))) * 8];
        acc[ct] = __builtin_amdgcn_mfma_f32_16x16x32_bf16(afr[ks], bb, acc[ct], 0, 0, 0);
      }
    }
    if (fcol >= 8) { acc[12][0] = -1e30f; acc[12][1] = -1e30f; acc[12][2] = -1e30f; acc[12][3] = -1e30f; }
    const float s2 = 0.08838834764831845f * 1.4426950408889634f;
    float wcp[13];
#pragma unroll
    for (int ct = 0; ct < 13; ++ct) wcp[ct] = 0.f;
#pragma unroll
    for (int r = 0; r < 4; ++r) {
      float m = acc[0][r];
#pragma unroll
      for (int ct = 1; ct < 13; ++ct) m = fmaxf(m, acc[ct][r]);
      m = fmaxf(m, __shfl_xor(m, 1));
      m = fmaxf(m, __shfl_xor(m, 2));
      m = fmaxf(m, __shfl_xor(m, 4));
      m = fmaxf(m, __shfl_xor(m, 8));
      float l = 0.f;
      float p[13];
#pragma unroll
      for (int ct = 0; ct < 13; ++ct) {
        p[ct] = fastexp2((acc[ct][r] - m) * s2);
        l += p[ct];
      }
      l += __shfl_xor(l, 1);
      l += __shfl_xor(l, 2);
      l += __shfl_xor(l, 4);
      l += __shfl_xor(l, 8);
      const float inv = fastrcp(l);
#pragma unroll
      for (int ct = 0; ct < 13; ++ct) wcp[ct] = fmaf(p[ct], inv, wcp[ct]);
    }
#pragma unroll
    for (int ct = 0; ct < 13; ++ct) {
      wcp[ct] += __shfl_xor(wcp[ct], 16);
      wcp[ct] += __shfl_xor(wcp[ct], 32);
      if (g == 0) wcsh[w][ct * 16 + fcol] = wcp[ct];
    }
  }
  float sc = -1e30f;
  if (tid < KK) {
    const float* br = B + (size_t)(b * KK + tid) * DDIM;
    float a = 0.f;
#pragma unroll
    for (int d4 = 0; d4 < 32; d4++) {
      float4 bb = *(const float4*)(br + d4 * 4);
      float4 ss = *(const float4*)(tq + d4 * 4);
      a += bb.x * ss.x + bb.y * ss.y + bb.z * ss.z + bb.w * ss.w;
    }
    sc = a * 0.08838834764831845f;
  }
  float mx = sc;
#pragma unroll
  for (int m = 1; m <= 32; m <<= 1) mx = fmaxf(mx, __shfl_xor(mx, m));
  if ((tid & 63) == 0) red1[tid >> 6] = mx;
  __syncthreads();
  mx = fmaxf(fmaxf(red1[0], red1[1]), fmaxf(red1[2], red1[3]));
  float p = (tid < KK) ? __expf(sc - mx) : 0.f;
  float sm = p;
#pragma unroll
  for (int m = 1; m <= 32; m <<= 1) sm += __shfl_xor(sm, m);
  if ((tid & 63) == 0) red2[tid >> 6] = sm;
  __syncthreads();
  sm = red2[0] + red2[1] + red2[2] + red2[3];
  if (tid < KK) ras[tid] = p / sm;
  if (tid < 208)
    wc[tid] = (wcsh[0][tid] + wcsh[1][tid] + wcsh[2][tid] + wcsh[3][tid]) * (1.f / 64.f);
  __syncthreads();
  {
    const int d = tid & 127, half = tid >> 7;
    float hd = 0.f, md = 0.f;
    const float* Bb = B + ((size_t)b * KK + half * 100) * DDIM + d;
    const float* rp = ras + half * 100;
    const float* wp = wc + half * 100;
#pragma unroll 2
    for (int c = 0; c < 100; ++c) {
      float bv = Bb[(size_t)c * DDIM];
      hd = fmaf(rp[c], bv, hd);
      md = fmaf(wp[c], bv, md);
    }
    hv2[tid] = hd; mv2[tid] = md;
  }
  __syncthreads();
  if (tid < 128) {
    hv[tid] = hv2[tid] + hv2[tid + 128];
    mv[tid] = mv2[tid] + mv2[tid + 128];
  }
  __syncthreads();
  if (tid < 64) {
    float x0 = mv[tid], x1 = mv[tid + 64];
    float s = x0 + x1, qq = x0 * x0 + x1 * x1;
#pragma unroll
    for (int m = 1; m <= 32; m <<= 1) { s += __shfl_xor(s, m); qq += __shfl_xor(qq, m); }
    if (tid == 0) { stats[0] = s; stats[1] = qq; }
  }
  __syncthreads();
  float mean = stats[0] * (1.f / 128.f);
  float var = stats[1] * (1.f / 128.f) - mean * mean;
  float rs = rsqrtf(var + 1e-5f);
  if (tid < 128) rv[tid] = hv[tid] + (mv[tid] - mean) * rs * memg[tid] + membt[tid];
  __syncthreads();
  if (tid < OUTN) {
    float a = headb[tid];
    for (int dd = 0; dd < 128; dd++) a = fmaf(rv[dd], headW[dd * OUTN + tid], a);
    out[b * OUTN + tid] = a;
  }
}

// ---------------------------------------------------------------------------
extern "C" void kernel_launch(void* const* d_in, const int* in_sizes, int n_in,
                              void* d_out, int out_size, void* d_ws, size_t ws_size,
                              hipStream_t stream) {
  (void)in_sizes; (void)n_in; (void)out_size; (void)ws_size;
  const float* x        = (const float*)d_in[0];
  const float* role_emb = (const float*)d_in[1];
  const float* filler_w = (const float*)d_in[2];
  const float* qW = (const float*)d_in[3];
  const float* qb = (const float*)d_in[4];
  const float* kW = (const float*)d_in[5];
  const float* kb = (const float*)d_in[6];
  const float* vW = (const float*)d_in[7];
  const float* vb = (const float*)d_in[8];
  const float* oW = (const float*)d_in[9];
  const float* ob = (const float*)d_in[10];
  const float* relW1 = (const float*)d_in[11];
  const float* relb1 = (const float*)d_in[12];
  const float* relW2 = (const float*)d_in[13];
  const float* relb2 = (const float*)d_in[14];
  const float* ln1g = (const float*)d_in[15];
  const float* ln1b = (const float*)d_in[16];
  const float* ln2g = (const float*)d_in[17];
  const float* ln2b = (const float*)d_in[18];
  const float* fW1 = (const float*)d_in[19];
  const float* fb1 = (const float*)d_in[20];
  const float* fW2 = (const float*)d_in[21];
  const float* fb2 = (const float*)d_in[22];
  const float* slots = (const float*)d_in[23];
  const float* memg = (const float*)d_in[24];
  const float* memb = (const float*)d_in[25];
  const float* taskq = (const float*)d_in[26];
  const float* headW = (const float*)d_in[27];
  const float* headb = (const float*)d_in[28];
  float* out = (float*)d_out;
  (void)relb2;  // dropped: softmax shift-invariance

  // workspace layout (float-slot offsets; all 16B aligned)
  float* fws  = (float*)d_ws;
  float*  btok   = fws;                       // 204800 f
  bf16_t* btokbf = (bf16_t*)(fws + 204800);   // 204800 bf16
  bf16_t* qbf    = (bf16_t*)(fws + 307200);   // 204800 bf16
  bf16_t* kbf    = (bf16_t*)(fws + 409600);   // 204800 bf16
  bf16_t* vbf    = (bf16_t*)(fws + 512000);   // 204800 bf16
  bf16_t* obufbf = (bf16_t*)(fws + 614400);   // 204800 bf16
  bf16_t* wtb    = (bf16_t*)(fws + 716800);   // 589824 bf16 (end ~4.0MB)
  bf16_t* qWt = wtb, *kWt = wtb + 49152, *vWt = wtb + 98304, *oWt = wtb + 147456;
  bf16_t* fW1t = wtb + 196608, *fW2t = wtb + 393216;

  prep_kernel<<<152, 256, 0, stream>>>(qW, kW, vW, oW, fW1, fW2, wtb,
      x, role_emb, filler_w, btok, btokbf);
  qkv_mfma<<<dim3(50, 3), 256, 0, stream>>>(btokbf,
      qWt, qb, kWt, kb, vWt, vb, qbf, kbf, vbf);
  for (int l = 0; l < LLAY; l++) {
    rel_attn_mfma<<<dim3(25, 32), 512, 0, stream>>>(qbf, kbf, vbf,
        relW1 + l * 3072, relb1 + l * 32, relW2 + l * 32, obufbf);
    const bool nx = (l + 1 < LLAY);
    tail_fused<<<100, 512, 0, stream>>>(obufbf, oWt + l * 16384, ob + l * 128,
        ln1g + l * 128, ln1b + l * 128, fW1t + l * 65536, fb1 + l * 512,
        fW2t + l * 65536, fb2 + l * 128, ln2g + l * 128, ln2b + l * 128,
        btok, btokbf,
        nx ? qWt + (l + 1) * 16384 : (const bf16_t*)nullptr,
        nx ? qb + (l + 1) * 128 : (const float*)nullptr,
        nx ? kWt + (l + 1) * 16384 : (const bf16_t*)nullptr,
        nx ? kb + (l + 1) * 128 : (const float*)nullptr,
        nx ? vWt + (l + 1) * 16384 : (const bf16_t*)nullptr,
        nx ? vb + (l + 1) * 128 : (const float*)nullptr,
        qbf, kbf, vbf);
  }
  readout_fused<<<8, 256, 0, stream>>>(btok, btokbf, slots, taskq,
      memg, memb, headW, headb, out);
}